// Round 7
// baseline (581.779 us; speedup 1.0000x reference)
//
#include <hip/hip_runtime.h>
#include <hip/hip_bf16.h>

#define HF 128   // feature/hidden dim (F == H == 128)
#define BSH 8    // bucket shift: 256 nodes per bucket
#define BSZ 256
#define NBMAX 1024
#define FCAP 8192

typedef __attribute__((ext_vector_type(8))) short bf16x8;
typedef __attribute__((ext_vector_type(4))) float f32x4;

__device__ inline float bflo(unsigned u) { return __uint_as_float(u << 16); }
__device__ inline float bfhi(unsigned u) { return __uint_as_float(u & 0xffff0000u); }
__device__ inline unsigned short f2bf(float f) {
    unsigned u = __float_as_uint(f);
    unsigned r = (u + 0x7fffu + ((u >> 16) & 1u)) >> 16;
    return (unsigned short)r;
}
__device__ inline unsigned pack2(float a, float b) {
    return (unsigned)f2bf(a) | ((unsigned)f2bf(b) << 16);
}

// ================= casts =================
__global__ __launch_bounds__(256) void cast_x(
    const float* __restrict__ x, unsigned short* __restrict__ xb, int nchunks)
{
    int i = blockIdx.x * 256 + threadIdx.x;
    if (i >= nchunks) return;
    float4 a = ((const float4*)x)[2 * i];
    float4 b = ((const float4*)x)[2 * i + 1];
    uint4 o;
    o.x = pack2(a.x, a.y); o.y = pack2(a.z, a.w);
    o.z = pack2(b.x, b.y); o.w = pack2(b.z, b.w);
    ((uint4*)xb)[i] = o;
}

__global__ void cast_wt(const float* __restrict__ w0, const float* __restrict__ w1,
                        const float* __restrict__ w2, const float* __restrict__ w3,
                        unsigned short* __restrict__ out)
{
    const float* W = (blockIdx.x == 0) ? w0 : (blockIdx.x == 1) ? w1
                   : (blockIdx.x == 2) ? w2 : w3;
    unsigned short* O = out + blockIdx.x * 16384;
    for (int idx = threadIdx.x; idx < 16384; idx += 256) {
        int n = idx >> 7, k = idx & 127;
        O[idx] = f2bf(W[k * 128 + n]);
    }
}

// ================= bucketed CSR build =================
__global__ __launch_bounds__(256) void bucket_hist(
    const int* __restrict__ dst, int* __restrict__ bcnt, int E, int NB, int chunk)
{
    __shared__ int lh[NBMAX];
    for (int i = threadIdx.x; i < NB; i += 256) lh[i] = 0;
    __syncthreads();
    int beg = blockIdx.x * chunk;
    int end = min(E, beg + chunk);
    for (int e = beg + threadIdx.x; e < end; e += 256)
        atomicAdd(&lh[dst[e] >> BSH], 1);
    __syncthreads();
    for (int i = threadIdx.x; i < NB; i += 256) {
        int c = lh[i];
        if (c) atomicAdd(&bcnt[i], c);
    }
}

__global__ void bucket_scan(const int* __restrict__ bcnt, int* __restrict__ boff,
                            int* __restrict__ bcur, int NB)
{
    __shared__ int part[256];
    int t = threadIdx.x;
    int v[4];
    int s = 0;
#pragma unroll
    for (int i = 0; i < 4; i++) {
        int idx = t * 4 + i;
        v[i] = (idx < NB) ? bcnt[idx] : 0;
        s += v[i];
    }
    part[t] = s;
    __syncthreads();
    for (int o = 1; o < 256; o <<= 1) {
        int y = (t >= o) ? part[t - o] : 0;
        __syncthreads();
        part[t] += y;
        __syncthreads();
    }
    int base = part[t] - s;
#pragma unroll
    for (int i = 0; i < 4; i++) {
        int idx = t * 4 + i;
        if (idx < NB) {
            boff[idx] = base;
            bcur[idx] = base;
            base += v[i];
        }
    }
    if (t == 255) boff[NB] = part[255];
}

__global__ __launch_bounds__(256) void bucket_bin(
    const int* __restrict__ src, const int* __restrict__ dst,
    int* __restrict__ bcur, unsigned* __restrict__ ebuf, int E, int NB, int chunk)
{
    __shared__ int lh[NBMAX];
    for (int i = threadIdx.x; i < NB; i += 256) lh[i] = 0;
    __syncthreads();
    int beg = blockIdx.x * chunk;
    int end = min(E, beg + chunk);
    for (int e = beg + threadIdx.x; e < end; e += 256)
        atomicAdd(&lh[dst[e] >> BSH], 1);
    __syncthreads();
    for (int i = threadIdx.x; i < NB; i += 256) {
        int c = lh[i];
        lh[i] = c ? atomicAdd(&bcur[i], c) : 0;
    }
    __syncthreads();
    for (int e = beg + threadIdx.x; e < end; e += 256) {
        int d = dst[e];
        int b = d >> BSH;
        int pos = atomicAdd(&lh[b], 1);
        ebuf[pos] = ((unsigned)src[e] << BSH) | (unsigned)(d & (BSZ - 1));
    }
}

__global__ __launch_bounds__(256) void bucket_fill(
    const unsigned* __restrict__ ebuf, const int* __restrict__ boff,
    int* __restrict__ off, int* __restrict__ esrc, int N, int NB, int E)
{
    __shared__ int deg[BSZ];
    __shared__ int pref[BSZ];
    __shared__ int lcur[BSZ];
    __shared__ int lsr[FCAP];
    int b = blockIdx.x;
    int t = threadIdx.x;
    int segBeg = boff[b], segEnd = boff[b + 1];
    int segLen = segEnd - segBeg;
    int node0 = b << BSH;
    deg[t] = 0;
    __syncthreads();
    for (int i = segBeg + t; i < segEnd; i += 256)
        atomicAdd(&deg[ebuf[i] & (BSZ - 1)], 1);
    __syncthreads();
    int dv = deg[t];
    pref[t] = dv;
    __syncthreads();
    for (int o = 1; o < 256; o <<= 1) {
        int y = (t >= o) ? pref[t - o] : 0;
        __syncthreads();
        pref[t] += y;
        __syncthreads();
    }
    int excl = pref[t] - dv;
    int node = node0 + t;
    if (node < N) off[node] = segBeg + excl;
    lcur[t] = excl;
    if (b == NB - 1 && t == 0) off[N] = E;
    __syncthreads();
    if (segLen <= FCAP) {
        for (int i = segBeg + t; i < segEnd; i += 256) {
            unsigned v = ebuf[i];
            int slot = atomicAdd(&lcur[v & (BSZ - 1)], 1);
            lsr[slot] = (int)(v >> BSH);
        }
        __syncthreads();
        for (int i = t; i < segLen; i += 256) esrc[segBeg + i] = lsr[i];
    } else {
        for (int i = segBeg + t; i < segEnd; i += 256) {
            unsigned v = ebuf[i];
            int slot = atomicAdd(&lcur[v & (BSZ - 1)], 1);
            esrc[segBeg + slot] = (int)(v >> BSH);
        }
    }
}

// ====== fused gather + double-GEMM + BN stats epilogue ======
// A-tile = gathered U rows ((1+eps)*x + sum_nbr x, optional BN fold), built
// directly in LDS. Then T = relu(A@Wa+ba) (stays in LDS), Hp = relu(T@Wb+bb)
// written bf16 with column stats accumulated into S1/S2.
#define AST 136
template <bool FOLD>
__global__ __launch_bounds__(256) void gemm2g(
    const unsigned short* __restrict__ Xsrc, const int* __restrict__ off,
    const int* __restrict__ esrc, const float* __restrict__ epsp,
    const float* __restrict__ scale, const float* __restrict__ shift,
    const unsigned short* __restrict__ Wta, const float* __restrict__ ba,
    const unsigned short* __restrict__ Wtb, const float* __restrict__ bb,
    unsigned short* __restrict__ out, float* __restrict__ S1, float* __restrict__ S2,
    int n)
{
    __shared__ unsigned short lA[64 * AST];
    __shared__ unsigned short lB[128 * AST];
    __shared__ float lS1[HF], lS2[HF];
    int tid = threadIdx.x;
    int row0 = blockIdx.x * 64;

    if (tid < HF) { lS1[tid] = 0.f; lS2[tid] = 0.f; }
    for (int c = tid; c < 2048; c += 256) {          // Wa -> lB
        int r = c >> 4, k16 = c & 15;
        *(uint4*)(&lB[r * AST + k16 * 8]) = *(const uint4*)(Wta + r * HF + k16 * 8);
    }

    // ---- fused gather into lA: 16 lanes/node, 16 nodes in flight ----
    float ep = 1.0f + epsp[0];
    int lane16 = tid & 15;
    int ng = tid >> 4;
    float4 fs0, fs1, fh0, fh1;
    if (FOLD) {
        fs0 = *(const float4*)(scale + lane16 * 8);
        fs1 = *(const float4*)(scale + lane16 * 8 + 4);
        fh0 = *(const float4*)(shift + lane16 * 8);
        fh1 = *(const float4*)(shift + lane16 * 8 + 4);
    }
    for (int rr = ng; rr < 64; rr += 16) {
        int node = row0 + rr;
        float acc[8] = {0.f, 0.f, 0.f, 0.f, 0.f, 0.f, 0.f, 0.f};
        if (node < n) {
            int beg = off[node], end = off[node + 1];
            for (int j0 = beg; j0 < end; j0 += 16) {
                int myidx = (j0 + lane16 < end) ? esrc[j0 + lane16] : 0;
                int cnt = min(16, end - j0);
                for (int t = 0; t < cnt; t++) {
                    int s = __shfl(myidx, t, 16);
                    uint4 pv = *(const uint4*)(Xsrc + (size_t)s * HF + lane16 * 8);
                    acc[0] += bflo(pv.x); acc[1] += bfhi(pv.x);
                    acc[2] += bflo(pv.y); acc[3] += bfhi(pv.y);
                    acc[4] += bflo(pv.z); acc[5] += bfhi(pv.z);
                    acc[6] += bflo(pv.w); acc[7] += bfhi(pv.w);
                }
            }
            uint4 xx = *(const uint4*)(Xsrc + (size_t)node * HF + lane16 * 8);
            acc[0] += ep * bflo(xx.x); acc[1] += ep * bfhi(xx.x);
            acc[2] += ep * bflo(xx.y); acc[3] += ep * bfhi(xx.y);
            acc[4] += ep * bflo(xx.z); acc[5] += ep * bfhi(xx.z);
            acc[6] += ep * bflo(xx.w); acc[7] += ep * bfhi(xx.w);
            if (FOLD) {
                float cf = ep + (float)(end - beg);
                acc[0] = acc[0] * fs0.x + fh0.x * cf; acc[1] = acc[1] * fs0.y + fh0.y * cf;
                acc[2] = acc[2] * fs0.z + fh0.z * cf; acc[3] = acc[3] * fs0.w + fh0.w * cf;
                acc[4] = acc[4] * fs1.x + fh1.x * cf; acc[5] = acc[5] * fs1.y + fh1.y * cf;
                acc[6] = acc[6] * fs1.z + fh1.z * cf; acc[7] = acc[7] * fs1.w + fh1.w * cf;
            }
        }
        uint4 o;
        o.x = pack2(acc[0], acc[1]); o.y = pack2(acc[2], acc[3]);
        o.z = pack2(acc[4], acc[5]); o.w = pack2(acc[6], acc[7]);
        *(uint4*)(&lA[rr * AST + lane16 * 8]) = o;
    }
    __syncthreads();

    int w = tid >> 6;
    int lane = tid & 63;
    int m = lane & 15, quad = lane >> 4;
    int wr = w & 1;
    int wc = w >> 1;

    f32x4 acc[2][4];
#pragma unroll
    for (int i = 0; i < 2; i++)
#pragma unroll
        for (int j = 0; j < 4; j++) acc[i][j] = (f32x4){0.f, 0.f, 0.f, 0.f};

#pragma unroll
    for (int kk = 0; kk < 4; kk++) {
        int ko = kk * 32 + quad * 8;
        bf16x8 a0 = *(const bf16x8*)(&lA[(wr * 32 + m) * AST + ko]);
        bf16x8 a1 = *(const bf16x8*)(&lA[(wr * 32 + 16 + m) * AST + ko]);
#pragma unroll
        for (int nt = 0; nt < 4; nt++) {
            bf16x8 b = *(const bf16x8*)(&lB[(wc * 64 + nt * 16 + m) * AST + ko]);
            acc[0][nt] = __builtin_amdgcn_mfma_f32_16x16x32_bf16(a0, b, acc[0][nt], 0, 0, 0);
            acc[1][nt] = __builtin_amdgcn_mfma_f32_16x16x32_bf16(a1, b, acc[1][nt], 0, 0, 0);
        }
    }
    __syncthreads();   // done reading lA (U) and lB (Wa)

    // T tile -> lA (relu(acc+ba), bf16); Wb -> lB
#pragma unroll
    for (int nt = 0; nt < 4; nt++) {
        int col = wc * 64 + nt * 16 + m;
        float bav = ba[col];
#pragma unroll
        for (int mt = 0; mt < 2; mt++) {
#pragma unroll
            for (int r = 0; r < 4; r++) {
                int lrow = wr * 32 + mt * 16 + quad * 4 + r;
                float v = fmaxf(acc[mt][nt][r] + bav, 0.f);
                lA[lrow * AST + col] = f2bf(v);
            }
        }
    }
    for (int c = tid; c < 2048; c += 256) {
        int r = c >> 4, k16 = c & 15;
        *(uint4*)(&lB[r * AST + k16 * 8]) = *(const uint4*)(Wtb + r * HF + k16 * 8);
    }
    __syncthreads();

#pragma unroll
    for (int i = 0; i < 2; i++)
#pragma unroll
        for (int j = 0; j < 4; j++) acc[i][j] = (f32x4){0.f, 0.f, 0.f, 0.f};

#pragma unroll
    for (int kk = 0; kk < 4; kk++) {
        int ko = kk * 32 + quad * 8;
        bf16x8 a0 = *(const bf16x8*)(&lA[(wr * 32 + m) * AST + ko]);
        bf16x8 a1 = *(const bf16x8*)(&lA[(wr * 32 + 16 + m) * AST + ko]);
#pragma unroll
        for (int nt = 0; nt < 4; nt++) {
            bf16x8 b = *(const bf16x8*)(&lB[(wc * 64 + nt * 16 + m) * AST + ko]);
            acc[0][nt] = __builtin_amdgcn_mfma_f32_16x16x32_bf16(a0, b, acc[0][nt], 0, 0, 0);
            acc[1][nt] = __builtin_amdgcn_mfma_f32_16x16x32_bf16(a1, b, acc[1][nt], 0, 0, 0);
        }
    }
    __syncthreads();   // about to overwrite lA with C

    // epilogue: relu + stats + C -> lA (bf16), then vectorized global store
#pragma unroll
    for (int nt = 0; nt < 4; nt++) {
        int col = wc * 64 + nt * 16 + m;
        float bbv = bb[col];
        float cs = 0.f, cq = 0.f;
#pragma unroll
        for (int mt = 0; mt < 2; mt++) {
#pragma unroll
            for (int r = 0; r < 4; r++) {
                int lrow = wr * 32 + mt * 16 + quad * 4 + r;
                int grow = row0 + lrow;
                float v = fmaxf(acc[mt][nt][r] + bbv, 0.f);
                lA[lrow * AST + col] = f2bf(v);
                if (grow < n) { cs += v; cq += v * v; }
            }
        }
        cs += __shfl_down(cs, 32); cs += __shfl_down(cs, 16);
        cq += __shfl_down(cq, 32); cq += __shfl_down(cq, 16);
        if (quad == 0) {
            atomicAdd(&lS1[col], cs);
            atomicAdd(&lS2[col], cq);
        }
    }
    __syncthreads();
    for (int c = tid; c < 1024; c += 256) {
        int r = c >> 4, k16 = c & 15;
        int grow = row0 + r;
        if (grow < n)
            *(uint4*)(out + (size_t)grow * HF + k16 * 8) = *(const uint4*)(&lA[r * AST + k16 * 8]);
    }
    if (tid < HF) {
        atomicAdd(&S1[tid], lS1[tid]);
        atomicAdd(&S2[tid], lS2[tid]);
    }
}

__global__ void bn_finalize(const float* __restrict__ S1, const float* __restrict__ S2,
                            const float* __restrict__ gamma, const float* __restrict__ beta,
                            float* __restrict__ scale, float* __restrict__ shift, float invN)
{
    int c = threadIdx.x;  // 128
    float mu = S1[c] * invN;
    float var = S2[c] * invN - mu * mu;
    float rs = rsqrtf(var + 1e-5f);
    float sc = gamma[c] * rs;
    scale[c] = sc;
    shift[c] = beta[c] - mu * sc;
}

// ---------------- graph segment bounds (batch sorted) ----------------
__global__ __launch_bounds__(256) void graph_bounds(
    const int* __restrict__ batch, int* __restrict__ gstart, int N, int Gn)
{
    int i = blockIdx.x * 256 + threadIdx.x;
    if (i >= N) return;
    int bi = batch[i];
    int bp = (i == 0) ? -1 : batch[i - 1];
    for (int g = bp + 1; g <= bi; g++) gstart[g] = i;
    if (i == N - 1) {
        for (int g = bi + 1; g <= Gn; g++) gstart[g] = N;
    }
}

// ------- pooled mean (BN2 folded) + lin1 + per-graph mse partial -------
// 512 threads = 8 waves; wave rg handles rows b+rg, b+rg+8, ...; lane c2
// holds column pair (2*c2, 2*c2+1). Wave-reduce gives the mse dot per row.
__global__ __launch_bounds__(512) void pool_tail(
    const unsigned short* __restrict__ h2raw,
    const float* __restrict__ scale, const float* __restrict__ shift,
    const int* __restrict__ gstart, const float* __restrict__ W,
    const float* __restrict__ bias,
    const float* __restrict__ Wloss, const float* __restrict__ blossp,
    const float* __restrict__ degree,
    float* __restrict__ z, float* __restrict__ partial)
{
    __shared__ float red[8][HF];
    __shared__ float gv[HF];
    __shared__ float part[4][HF];
    __shared__ float wred[8];
    int gid = blockIdx.x;
    int t = threadIdx.x;
    int c2 = t & 63;
    int rg = t >> 6;
    int b = gstart[gid], e = gstart[gid + 1];
    float wla = scale[2 * c2] * Wloss[2 * c2];
    float wlb = scale[2 * c2 + 1] * Wloss[2 * c2 + 1];
    float c0l = shift[2 * c2] * Wloss[2 * c2] + shift[2 * c2 + 1] * Wloss[2 * c2 + 1];
    float bl = blossp[0];
    float s0 = 0.f, s1 = 0.f, macc = 0.f;
    for (int r = b + rg; r < e; r += 8) {
        unsigned u = *(const unsigned*)(h2raw + (size_t)r * HF + c2 * 2);
        float v0 = bflo(u), v1 = bfhi(u);
        s0 += v0; s1 += v1;
        float m = v0 * wla + v1 * wlb + c0l;
#pragma unroll
        for (int o = 32; o > 0; o >>= 1) m += __shfl_down(m, o);
        if (c2 == 0) {
            float d = m + bl - degree[r];
            macc += d * d;
        }
    }
    red[rg][c2 * 2] = s0;
    red[rg][c2 * 2 + 1] = s1;
    if (c2 == 0) wred[rg] = macc;
    __syncthreads();
    if (t < HF) {
        float s = red[0][t] + red[1][t] + red[2][t] + red[3][t]
                + red[4][t] + red[5][t] + red[6][t] + red[7][t];
        gv[t] = (e > b) ? scale[t] * (s / (float)(e - b)) + shift[t] : 0.f;
    }
    __syncthreads();
    int c = t & 127, kg = t >> 7;  // 4 k-groups of 32
    float a = 0.f;
#pragma unroll 8
    for (int k = kg * 32; k < kg * 32 + 32; k++) a += gv[k] * W[(size_t)k * HF + c];
    part[kg][c] = a;
    __syncthreads();
    if (t < HF) {
        float aa = part[0][t] + part[1][t] + part[2][t] + part[3][t] + bias[t];
        z[(size_t)gid * HF + t] = fmaxf(aa, 0.f);
    }
    if (t == 0)
        partial[gid] = wred[0] + wred[1] + wred[2] + wred[3]
                     + wred[4] + wred[5] + wred[6] + wred[7];
}

__global__ void mse_final(const float* __restrict__ partial, float* __restrict__ out,
                          float invN, int P)
{
    __shared__ float sd[256];
    int t = threadIdx.x;
    float s = 0.f;
    for (int i = t; i < P; i += 256) s += partial[i];
    sd[t] = s;
    __syncthreads();
    for (int o = 128; o > 0; o >>= 1) {
        if (t < o) sd[t] += sd[t + o];
        __syncthreads();
    }
    if (t == 0) out[0] = sd[0] * invN;
}

// ---------------- heads
__global__ void heads(const float* __restrict__ z, const float* __restrict__ W2,
                      const float* __restrict__ b2, const float* __restrict__ W4,
                      const float* __restrict__ b4, float* __restrict__ out1,
                      float* __restrict__ out3, int C_, int D_)
{
    __shared__ float zr[HF];
    __shared__ float logits[16];
    __shared__ float lse_s;
    int gid = blockIdx.x;
    int t = threadIdx.x;  // 64
    zr[t] = z[(size_t)gid * HF + t];
    zr[t + 64] = z[(size_t)gid * HF + t + 64];
    __syncthreads();
    if (t < C_) {
        float a = b2[t];
        for (int k = 0; k < HF; k++) a += zr[k] * W2[(size_t)k * C_ + t];
        logits[t] = a;
    }
    __syncthreads();
    if (t == 0) {
        float mx = -1e30f;
        for (int i = 0; i < C_; i++) mx = fmaxf(mx, logits[i]);
        float s = 0.f;
        for (int i = 0; i < C_; i++) s += expf(logits[i] - mx);
        lse_s = mx + logf(s);
    }
    __syncthreads();
    if (t < C_) out1[(size_t)gid * C_ + t] = logits[t] - lse_s;
    if (t < D_) {
        float a = b4[t];
        for (int k = 0; k < HF; k++) a += zr[k] * W4[(size_t)k * D_ + t];
        out3[(size_t)gid * D_ + t] = a;
    }
}

extern "C" void kernel_launch(void* const* d_in, const int* in_sizes, int n_in,
                              void* d_out, int out_size, void* d_ws, size_t ws_size,
                              hipStream_t stream)
{
    const float* x      = (const float*)d_in[0];
    const int*   ei     = (const int*)d_in[1];
    const int*   batch  = (const int*)d_in[2];
    const float* degree = (const float*)d_in[3];
    const float* eps1   = (const float*)d_in[4];
    const float* W1a    = (const float*)d_in[5];
    const float* b1a    = (const float*)d_in[6];
    const float* W1b    = (const float*)d_in[7];
    const float* b1b    = (const float*)d_in[8];
    const float* g1     = (const float*)d_in[9];
    const float* be1    = (const float*)d_in[10];
    const float* eps2   = (const float*)d_in[11];
    const float* W2a    = (const float*)d_in[12];
    const float* b2a    = (const float*)d_in[13];
    const float* W2b    = (const float*)d_in[14];
    const float* b2b    = (const float*)d_in[15];
    const float* g2     = (const float*)d_in[16];
    const float* be2    = (const float*)d_in[17];
    const float* Wlin1  = (const float*)d_in[18];
    const float* blin1  = (const float*)d_in[19];
    const float* Wlin2  = (const float*)d_in[20];
    const float* blin2  = (const float*)d_in[21];
    const float* Wlin4  = (const float*)d_in[22];
    const float* blin4  = (const float*)d_in[23];
    const float* Wloss  = (const float*)d_in[24];
    const float* bloss  = (const float*)d_in[25];

    const int N  = in_sizes[0] / HF;
    const int E  = in_sizes[1] / 2;
    const int C_ = in_sizes[21];
    const int D_ = in_sizes[23];
    const int Gn = (out_size - 1) / (C_ + D_);
    const int NB = (N + BSZ - 1) >> BSH;

    const int* src = ei;
    const int* dst = ei + E;

    size_t NH = (size_t)N * HF;
    char* p = (char*)d_ws;
    unsigned short* xb  = (unsigned short*)p; p += NH * 2;
    unsigned short* Hp1 = (unsigned short*)p; p += NH * 2;
    unsigned short* Hp2 = (unsigned short*)p; p += NH * 2;
    unsigned short* WtAll = (unsigned short*)p; p += 4 * 16384 * 2;
    float* S1    = (float*)p; p += HF * 4;
    float* S2    = (float*)p; p += HF * 4;
    float* scale = (float*)p; p += HF * 4;
    float* shift = (float*)p; p += HF * 4;
    float* z       = (float*)p; p += (size_t)Gn * HF * 4;
    float* partial = (float*)p; p += 1024 * 4;
    int* gstart = (int*)p; p += (Gn + 1) * 4;
    int* bcnt   = (int*)p; p += NBMAX * 4;
    int* boff   = (int*)p; p += (NBMAX + 1) * 4;
    int* bcur   = (int*)p; p += NBMAX * 4;
    int* off    = (int*)p; p += (N + 1) * 4;
    int* esrc   = (int*)p; p += E * 4;
    unsigned* ebuf = (unsigned*)p; p += E * 4;

    unsigned short* Wt1a = WtAll;
    unsigned short* Wt1b = WtAll + 16384;
    unsigned short* Wt2a = WtAll + 32768;
    unsigned short* Wt2b = WtAll + 49152;

    float* out1 = (float*)d_out;
    float* out3 = out1 + (size_t)Gn * C_;
    float* outm = out3 + (size_t)Gn * D_;

    int nBlocks   = (N + 255) / 256;
    int castBlk   = ((int)(NH / 8) + 255) / 256;
    int gemmBlk   = (N + 63) / 64;
    const int BINB = 512;
    int chunk = (E + BINB - 1) / BINB;
    float invN = 1.0f / (float)N;

    // ---- casts + CSR + bounds ----
    cast_x<<<castBlk, 256, 0, stream>>>(x, xb, (int)(NH / 8));
    cast_wt<<<4, 256, 0, stream>>>(W1a, W1b, W2a, W2b, WtAll);
    hipMemsetAsync(bcnt, 0, NB * sizeof(int), stream);
    bucket_hist<<<BINB, 256, 0, stream>>>(dst, bcnt, E, NB, chunk);
    bucket_scan<<<1, 256, 0, stream>>>(bcnt, boff, bcur, NB);
    bucket_bin<<<BINB, 256, 0, stream>>>(src, dst, bcur, ebuf, E, NB, chunk);
    bucket_fill<<<NB, 256, 0, stream>>>(ebuf, boff, off, esrc, N, NB, E);
    graph_bounds<<<nBlocks, 256, 0, stream>>>(batch, gstart, N, Gn);

    // ---- layer 1: gather+GEMM+GEMM+stats in one kernel ----
    hipMemsetAsync(S1, 0, 2 * HF * sizeof(float), stream);
    gemm2g<false><<<gemmBlk, 256, 0, stream>>>(xb, off, esrc, eps1, nullptr, nullptr,
                                               Wt1a, b1a, Wt1b, b1b, Hp1, S1, S2, N);
    bn_finalize<<<1, 128, 0, stream>>>(S1, S2, g1, be1, scale, shift, invN);

    // ---- layer 2: BN1 folded into gather; BN2 folded into tail ----
    hipMemsetAsync(S1, 0, 2 * HF * sizeof(float), stream);
    gemm2g<true><<<gemmBlk, 256, 0, stream>>>(Hp1, off, esrc, eps2, scale, shift,
                                              Wt2a, b2a, Wt2b, b2b, Hp2, S1, S2, N);
    bn_finalize<<<1, 128, 0, stream>>>(S1, S2, g2, be2, scale, shift, invN);

    // ---- tail ----
    pool_tail<<<Gn, 512, 0, stream>>>(Hp2, scale, shift, gstart, Wlin1, blin1,
                                      Wloss, bloss, degree, z, partial);
    mse_final<<<1, 256, 0, stream>>>(partial, outm, invN, Gn);
    heads<<<Gn, 64, 0, stream>>>(z, Wlin2, blin2, Wlin4, blin4, out1, out3, C_, D_);
}

// Round 8
// 547.451 us; speedup vs baseline: 1.0627x; 1.0627x over previous
//
#include <hip/hip_runtime.h>
#include <hip/hip_bf16.h>

#define HF 128   // feature/hidden dim (F == H == 128)
#define BSH 8    // bucket shift: 256 nodes per bucket
#define BSZ 256
#define NBMAX 1024
#define FCAP 8192
#define AST 136  // padded LDS row stride (bf16 elems)

typedef __attribute__((ext_vector_type(8))) short bf16x8;
typedef __attribute__((ext_vector_type(4))) float f32x4;

__device__ inline float bflo(unsigned u) { return __uint_as_float(u << 16); }
__device__ inline float bfhi(unsigned u) { return __uint_as_float(u & 0xffff0000u); }
__device__ inline unsigned short f2bf(float f) {
    unsigned u = __float_as_uint(f);
    unsigned r = (u + 0x7fffu + ((u >> 16) & 1u)) >> 16;
    return (unsigned short)r;
}
__device__ inline unsigned pack2(float a, float b) {
    return (unsigned)f2bf(a) | ((unsigned)f2bf(b) << 16);
}

// ================= casts =================
__global__ __launch_bounds__(256) void cast_x(
    const float* __restrict__ x, unsigned short* __restrict__ xb, int nchunks)
{
    int i = blockIdx.x * 256 + threadIdx.x;
    if (i >= nchunks) return;
    float4 a = ((const float4*)x)[2 * i];
    float4 b = ((const float4*)x)[2 * i + 1];
    uint4 o;
    o.x = pack2(a.x, a.y); o.y = pack2(a.z, a.w);
    o.z = pack2(b.x, b.y); o.w = pack2(b.z, b.w);
    ((uint4*)xb)[i] = o;
}

__global__ void cast_wt(const float* __restrict__ w0, const float* __restrict__ w1,
                        const float* __restrict__ w2, const float* __restrict__ w3,
                        unsigned short* __restrict__ out)
{
    const float* W = (blockIdx.x == 0) ? w0 : (blockIdx.x == 1) ? w1
                   : (blockIdx.x == 2) ? w2 : w3;
    unsigned short* O = out + blockIdx.x * 16384;
    for (int idx = threadIdx.x; idx < 16384; idx += 256) {
        int n = idx >> 7, k = idx & 127;
        O[idx] = f2bf(W[k * 128 + n]);
    }
}

// ================= bucketed CSR build =================
__global__ __launch_bounds__(256) void bucket_hist(
    const int* __restrict__ dst, int* __restrict__ bcnt, int E, int NB, int chunk)
{
    __shared__ int lh[NBMAX];
    for (int i = threadIdx.x; i < NB; i += 256) lh[i] = 0;
    __syncthreads();
    int beg = blockIdx.x * chunk;
    int end = min(E, beg + chunk);
    for (int e = beg + threadIdx.x; e < end; e += 256)
        atomicAdd(&lh[dst[e] >> BSH], 1);
    __syncthreads();
    for (int i = threadIdx.x; i < NB; i += 256) {
        int c = lh[i];
        if (c) atomicAdd(&bcnt[i], c);
    }
}

__global__ void bucket_scan(const int* __restrict__ bcnt, int* __restrict__ boff,
                            int* __restrict__ bcur, int NB)
{
    __shared__ int part[256];
    int t = threadIdx.x;
    int v[4];
    int s = 0;
#pragma unroll
    for (int i = 0; i < 4; i++) {
        int idx = t * 4 + i;
        v[i] = (idx < NB) ? bcnt[idx] : 0;
        s += v[i];
    }
    part[t] = s;
    __syncthreads();
    for (int o = 1; o < 256; o <<= 1) {
        int y = (t >= o) ? part[t - o] : 0;
        __syncthreads();
        part[t] += y;
        __syncthreads();
    }
    int base = part[t] - s;
#pragma unroll
    for (int i = 0; i < 4; i++) {
        int idx = t * 4 + i;
        if (idx < NB) {
            boff[idx] = base;
            bcur[idx] = base;
            base += v[i];
        }
    }
    if (t == 255) boff[NB] = part[255];
}

__global__ __launch_bounds__(256) void bucket_bin(
    const int* __restrict__ src, const int* __restrict__ dst,
    int* __restrict__ bcur, unsigned* __restrict__ ebuf, int E, int NB, int chunk)
{
    __shared__ int lh[NBMAX];
    for (int i = threadIdx.x; i < NB; i += 256) lh[i] = 0;
    __syncthreads();
    int beg = blockIdx.x * chunk;
    int end = min(E, beg + chunk);
    for (int e = beg + threadIdx.x; e < end; e += 256)
        atomicAdd(&lh[dst[e] >> BSH], 1);
    __syncthreads();
    for (int i = threadIdx.x; i < NB; i += 256) {
        int c = lh[i];
        lh[i] = c ? atomicAdd(&bcur[i], c) : 0;
    }
    __syncthreads();
    for (int e = beg + threadIdx.x; e < end; e += 256) {
        int d = dst[e];
        int b = d >> BSH;
        int pos = atomicAdd(&lh[b], 1);
        ebuf[pos] = ((unsigned)src[e] << BSH) | (unsigned)(d & (BSZ - 1));
    }
}

__global__ __launch_bounds__(256) void bucket_fill(
    const unsigned* __restrict__ ebuf, const int* __restrict__ boff,
    int* __restrict__ off, int* __restrict__ esrc, int N, int NB, int E)
{
    __shared__ int deg[BSZ];
    __shared__ int pref[BSZ];
    __shared__ int lcur[BSZ];
    __shared__ int lsr[FCAP];
    int b = blockIdx.x;
    int t = threadIdx.x;
    int segBeg = boff[b], segEnd = boff[b + 1];
    int segLen = segEnd - segBeg;
    int node0 = b << BSH;
    deg[t] = 0;
    __syncthreads();
    for (int i = segBeg + t; i < segEnd; i += 256)
        atomicAdd(&deg[ebuf[i] & (BSZ - 1)], 1);
    __syncthreads();
    int dv = deg[t];
    pref[t] = dv;
    __syncthreads();
    for (int o = 1; o < 256; o <<= 1) {
        int y = (t >= o) ? pref[t - o] : 0;
        __syncthreads();
        pref[t] += y;
        __syncthreads();
    }
    int excl = pref[t] - dv;
    int node = node0 + t;
    if (node < N) off[node] = segBeg + excl;
    lcur[t] = excl;
    if (b == NB - 1 && t == 0) off[N] = E;
    __syncthreads();
    if (segLen <= FCAP) {
        for (int i = segBeg + t; i < segEnd; i += 256) {
            unsigned v = ebuf[i];
            int slot = atomicAdd(&lcur[v & (BSZ - 1)], 1);
            lsr[slot] = (int)(v >> BSH);
        }
        __syncthreads();
        for (int i = t; i < segLen; i += 256) esrc[segBeg + i] = lsr[i];
    } else {
        for (int i = segBeg + t; i < segEnd; i += 256) {
            unsigned v = ebuf[i];
            int slot = atomicAdd(&lcur[v & (BSZ - 1)], 1);
            esrc[segBeg + slot] = (int)(v >> BSH);
        }
    }
}

// ============ gather + fused U, bf16 in/out; optional BN1 affine fold ========
template <bool FOLD>
__global__ __launch_bounds__(256) void gather_u(
    const unsigned short* __restrict__ xb, const int* __restrict__ off,
    const int* __restrict__ esrc, const float* __restrict__ epsp,
    const float* __restrict__ scale, const float* __restrict__ shift,
    unsigned short* __restrict__ Uo, int N)
{
    int lane16 = threadIdx.x & 15;
    int node = (blockIdx.x * 256 + threadIdx.x) >> 4;
    if (node >= N) return;
    int beg = off[node], end = off[node + 1];
    float acc[8] = {0.f, 0.f, 0.f, 0.f, 0.f, 0.f, 0.f, 0.f};
    for (int j0 = beg; j0 < end; j0 += 16) {
        int myidx = (j0 + lane16 < end) ? esrc[j0 + lane16] : 0;
        int cnt = min(16, end - j0);
        for (int t = 0; t < cnt; t++) {
            int s = __shfl(myidx, t, 16);
            uint4 p = *(const uint4*)(xb + (size_t)s * HF + lane16 * 8);
            acc[0] += bflo(p.x); acc[1] += bfhi(p.x);
            acc[2] += bflo(p.y); acc[3] += bfhi(p.y);
            acc[4] += bflo(p.z); acc[5] += bfhi(p.z);
            acc[6] += bflo(p.w); acc[7] += bfhi(p.w);
        }
    }
    float ep = 1.0f + epsp[0];
    uint4 xx = *(const uint4*)(xb + (size_t)node * HF + lane16 * 8);
    acc[0] += ep * bflo(xx.x); acc[1] += ep * bfhi(xx.x);
    acc[2] += ep * bflo(xx.y); acc[3] += ep * bfhi(xx.y);
    acc[4] += ep * bflo(xx.z); acc[5] += ep * bfhi(xx.z);
    acc[6] += ep * bflo(xx.w); acc[7] += ep * bfhi(xx.w);
    if (FOLD) {
        float cnt = ep + (float)(end - beg);
        const float4 s0 = *(const float4*)(scale + lane16 * 8);
        const float4 s1 = *(const float4*)(scale + lane16 * 8 + 4);
        const float4 h0 = *(const float4*)(shift + lane16 * 8);
        const float4 h1 = *(const float4*)(shift + lane16 * 8 + 4);
        acc[0] = acc[0] * s0.x + h0.x * cnt; acc[1] = acc[1] * s0.y + h0.y * cnt;
        acc[2] = acc[2] * s0.z + h0.z * cnt; acc[3] = acc[3] * s0.w + h0.w * cnt;
        acc[4] = acc[4] * s1.x + h1.x * cnt; acc[5] = acc[5] * s1.y + h1.y * cnt;
        acc[6] = acc[6] * s1.z + h1.z * cnt; acc[7] = acc[7] * s1.w + h1.w * cnt;
    }
    uint4 o;
    o.x = pack2(acc[0], acc[1]); o.y = pack2(acc[2], acc[3]);
    o.z = pack2(acc[4], acc[5]); o.w = pack2(acc[6], acc[7]);
    *(uint4*)(Uo + (size_t)node * HF + lane16 * 8) = o;
}

// ====== double-GEMM, wave-independent tiling ======
// Wave = 16 rows x 128 cols. A-frags from global U; B-frags JIT from global Wt
// (L2-hot); T round-trips LDS in the wave's OWN rows only -> no pipeline
// barriers. Epilogue: bias+relu+column-stats+vectorized store.
__global__ __launch_bounds__(256) void gemm2r(
    const unsigned short* __restrict__ U,
    const unsigned short* __restrict__ Wta, const float* __restrict__ ba,
    const unsigned short* __restrict__ Wtb, const float* __restrict__ bb,
    unsigned short* __restrict__ out, float* __restrict__ S1, float* __restrict__ S2,
    int n)
{
    __shared__ unsigned short lT[64 * AST];
    __shared__ float lS1[HF], lS2[HF];
    int tid = threadIdx.x;
    int w = tid >> 6, lane = tid & 63;
    int m = lane & 15, quad = lane >> 4;
    int row0 = blockIdx.x * 64;
    if (tid < HF) { lS1[tid] = 0.f; lS2[tid] = 0.f; }
    __syncthreads();

    int arow = row0 + w * 16 + m;
    if (arow >= n) arow = n - 1;   // clamp; stats/stores guarded below
    bf16x8 aF[4];
#pragma unroll
    for (int kk = 0; kk < 4; kk++)
        aF[kk] = *(const bf16x8*)(U + (size_t)arow * HF + kk * 32 + quad * 8);

    f32x4 acc[8];
#pragma unroll
    for (int nt = 0; nt < 8; nt++) acc[nt] = (f32x4){0.f, 0.f, 0.f, 0.f};
#pragma unroll
    for (int nt = 0; nt < 8; nt++) {
#pragma unroll
        for (int kk = 0; kk < 4; kk++) {
            bf16x8 b = *(const bf16x8*)(Wta + (size_t)(nt * 16 + m) * HF + kk * 32 + quad * 8);
            acc[nt] = __builtin_amdgcn_mfma_f32_16x16x32_bf16(aF[kk], b, acc[nt], 0, 0, 0);
        }
    }
    // T = relu(acc + ba) -> lT (own 16 rows; no cross-wave sharing)
#pragma unroll
    for (int nt = 0; nt < 8; nt++) {
        float bav = ba[nt * 16 + m];
#pragma unroll
        for (int r = 0; r < 4; r++) {
            int lrow = w * 16 + quad * 4 + r;
            lT[lrow * AST + nt * 16 + m] = f2bf(fmaxf(acc[nt][r] + bav, 0.f));
        }
    }
    // stage 2: A-frags from lT (own rows)
#pragma unroll
    for (int kk = 0; kk < 4; kk++)
        aF[kk] = *(const bf16x8*)(&lT[(w * 16 + m) * AST + kk * 32 + quad * 8]);
#pragma unroll
    for (int nt = 0; nt < 8; nt++) acc[nt] = (f32x4){0.f, 0.f, 0.f, 0.f};
#pragma unroll
    for (int nt = 0; nt < 8; nt++) {
#pragma unroll
        for (int kk = 0; kk < 4; kk++) {
            bf16x8 b = *(const bf16x8*)(Wtb + (size_t)(nt * 16 + m) * HF + kk * 32 + quad * 8);
            acc[nt] = __builtin_amdgcn_mfma_f32_16x16x32_bf16(aF[kk], b, acc[nt], 0, 0, 0);
        }
    }
    // epilogue: relu + stats + C -> lT (own rows)
#pragma unroll
    for (int nt = 0; nt < 8; nt++) {
        int col = nt * 16 + m;
        float bbv = bb[col];
        float cs = 0.f, cq = 0.f;
#pragma unroll
        for (int r = 0; r < 4; r++) {
            int lrow = w * 16 + quad * 4 + r;
            int grow = row0 + lrow;
            float v = fmaxf(acc[nt][r] + bbv, 0.f);
            lT[lrow * AST + col] = f2bf(v);
            if (grow < n) { cs += v; cq += v * v; }
        }
        cs += __shfl_down(cs, 32); cs += __shfl_down(cs, 16);
        cq += __shfl_down(cq, 32); cq += __shfl_down(cq, 16);
        if (quad == 0) { atomicAdd(&lS1[col], cs); atomicAdd(&lS2[col], cq); }
    }
    // vectorized store of own rows
#pragma unroll
    for (int i = 0; i < 4; i++) {
        int idx = i * 64 + lane;
        int r = idx >> 4, k16 = idx & 15;
        int grow = row0 + w * 16 + r;
        if (grow < n)
            *(uint4*)(out + (size_t)grow * HF + k16 * 8) =
                *(const uint4*)(&lT[(w * 16 + r) * AST + k16 * 8]);
    }
    __syncthreads();
    if (tid < HF) { atomicAdd(&S1[tid], lS1[tid]); atomicAdd(&S2[tid], lS2[tid]); }
}

__global__ void bn_finalize(const float* __restrict__ S1, const float* __restrict__ S2,
                            const float* __restrict__ gamma, const float* __restrict__ beta,
                            float* __restrict__ scale, float* __restrict__ shift, float invN)
{
    int c = threadIdx.x;  // 128
    float mu = S1[c] * invN;
    float var = S2[c] * invN - mu * mu;
    float rs = rsqrtf(var + 1e-5f);
    float sc = gamma[c] * rs;
    scale[c] = sc;
    shift[c] = beta[c] - mu * sc;
}

// ---------------- graph segment bounds (batch sorted) ----------------
__global__ __launch_bounds__(256) void graph_bounds(
    const int* __restrict__ batch, int* __restrict__ gstart, int N, int Gn)
{
    int i = blockIdx.x * 256 + threadIdx.x;
    if (i >= N) return;
    int bi = batch[i];
    int bp = (i == 0) ? -1 : batch[i - 1];
    for (int g = bp + 1; g <= bi; g++) gstart[g] = i;
    if (i == N - 1) {
        for (int g = bi + 1; g <= Gn; g++) gstart[g] = N;
    }
}

// ------- pool (BN2 folded) + lin1 + mse partial + heads, one kernel/graph ---
__global__ __launch_bounds__(512) void pool_tail(
    const unsigned short* __restrict__ h2raw,
    const float* __restrict__ scale, const float* __restrict__ shift,
    const int* __restrict__ gstart, const float* __restrict__ W,
    const float* __restrict__ bias,
    const float* __restrict__ Wloss, const float* __restrict__ blossp,
    const float* __restrict__ degree,
    const float* __restrict__ W2, const float* __restrict__ b2,
    const float* __restrict__ W4, const float* __restrict__ b4,
    float* __restrict__ out1, float* __restrict__ out3,
    float* __restrict__ partial, int C_, int D_)
{
    __shared__ float red[8][HF];
    __shared__ float gv[HF];
    __shared__ float part[4][HF];
    __shared__ float wred[8];
    __shared__ float zz[HF];
    __shared__ float logits[16];
    __shared__ float lse_s;
    int gid = blockIdx.x;
    int t = threadIdx.x;
    int c2 = t & 63;
    int rg = t >> 6;
    int b = gstart[gid], e = gstart[gid + 1];
    float wla = scale[2 * c2] * Wloss[2 * c2];
    float wlb = scale[2 * c2 + 1] * Wloss[2 * c2 + 1];
    float c0l = shift[2 * c2] * Wloss[2 * c2] + shift[2 * c2 + 1] * Wloss[2 * c2 + 1];
    float bl = blossp[0];
    float s0 = 0.f, s1 = 0.f, macc = 0.f;
    for (int r = b + rg; r < e; r += 8) {
        unsigned u = *(const unsigned*)(h2raw + (size_t)r * HF + c2 * 2);
        float v0 = bflo(u), v1 = bfhi(u);
        s0 += v0; s1 += v1;
        float m = v0 * wla + v1 * wlb + c0l;
#pragma unroll
        for (int o = 32; o > 0; o >>= 1) m += __shfl_down(m, o);
        if (c2 == 0) {
            float d = m + bl - degree[r];
            macc += d * d;
        }
    }
    red[rg][c2 * 2] = s0;
    red[rg][c2 * 2 + 1] = s1;
    if (c2 == 0) wred[rg] = macc;
    __syncthreads();
    if (t < HF) {
        float s = red[0][t] + red[1][t] + red[2][t] + red[3][t]
                + red[4][t] + red[5][t] + red[6][t] + red[7][t];
        gv[t] = (e > b) ? scale[t] * (s / (float)(e - b)) + shift[t] : 0.f;
    }
    __syncthreads();
    int c = t & 127, kg = t >> 7;  // 4 k-groups of 32
    float a = 0.f;
#pragma unroll 8
    for (int k = kg * 32; k < kg * 32 + 32; k++) a += gv[k] * W[(size_t)k * HF + c];
    part[kg][c] = a;
    __syncthreads();
    if (t < HF) {
        float aa = part[0][t] + part[1][t] + part[2][t] + part[3][t] + bias[t];
        zz[t] = fmaxf(aa, 0.f);
    }
    if (t == 0)
        partial[gid] = wred[0] + wred[1] + wred[2] + wred[3]
                     + wred[4] + wred[5] + wred[6] + wred[7];
    __syncthreads();
    if (t < C_) {
        float aa = b2[t];
        for (int k = 0; k < HF; k++) aa += zz[k] * W2[(size_t)k * C_ + t];
        logits[t] = aa;
    }
    __syncthreads();
    if (t == 0) {
        float mx = -1e30f;
        for (int i = 0; i < C_; i++) mx = fmaxf(mx, logits[i]);
        float s = 0.f;
        for (int i = 0; i < C_; i++) s += expf(logits[i] - mx);
        lse_s = mx + logf(s);
    }
    __syncthreads();
    if (t < C_) out1[(size_t)gid * C_ + t] = logits[t] - lse_s;
    if (t < D_) {
        float aa = b4[t];
        for (int k = 0; k < HF; k++) aa += zz[k] * W4[(size_t)k * D_ + t];
        out3[(size_t)gid * D_ + t] = aa;
    }
}

__global__ void mse_final(const float* __restrict__ partial, float* __restrict__ out,
                          float invN, int P)
{
    __shared__ float sd[256];
    int t = threadIdx.x;
    float s = 0.f;
    for (int i = t; i < P; i += 256) s += partial[i];
    sd[t] = s;
    __syncthreads();
    for (int o = 128; o > 0; o >>= 1) {
        if (t < o) sd[t] += sd[t + o];
        __syncthreads();
    }
    if (t == 0) out[0] = sd[0] * invN;
}

extern "C" void kernel_launch(void* const* d_in, const int* in_sizes, int n_in,
                              void* d_out, int out_size, void* d_ws, size_t ws_size,
                              hipStream_t stream)
{
    const float* x      = (const float*)d_in[0];
    const int*   ei     = (const int*)d_in[1];
    const int*   batch  = (const int*)d_in[2];
    const float* degree = (const float*)d_in[3];
    const float* eps1   = (const float*)d_in[4];
    const float* W1a    = (const float*)d_in[5];
    const float* b1a    = (const float*)d_in[6];
    const float* W1b    = (const float*)d_in[7];
    const float* b1b    = (const float*)d_in[8];
    const float* g1     = (const float*)d_in[9];
    const float* be1    = (const float*)d_in[10];
    const float* eps2   = (const float*)d_in[11];
    const float* W2a    = (const float*)d_in[12];
    const float* b2a    = (const float*)d_in[13];
    const float* W2b    = (const float*)d_in[14];
    const float* b2b    = (const float*)d_in[15];
    const float* g2     = (const float*)d_in[16];
    const float* be2    = (const float*)d_in[17];
    const float* Wlin1  = (const float*)d_in[18];
    const float* blin1  = (const float*)d_in[19];
    const float* Wlin2  = (const float*)d_in[20];
    const float* blin2  = (const float*)d_in[21];
    const float* Wlin4  = (const float*)d_in[22];
    const float* blin4  = (const float*)d_in[23];
    const float* Wloss  = (const float*)d_in[24];
    const float* bloss  = (const float*)d_in[25];

    const int N  = in_sizes[0] / HF;
    const int E  = in_sizes[1] / 2;
    const int C_ = in_sizes[21];
    const int D_ = in_sizes[23];
    const int Gn = (out_size - 1) / (C_ + D_);
    const int NB = (N + BSZ - 1) >> BSH;

    const int* src = ei;
    const int* dst = ei + E;

    size_t NH = (size_t)N * HF;
    char* p = (char*)d_ws;
    unsigned short* xb  = (unsigned short*)p; p += NH * 2;
    unsigned short* U   = (unsigned short*)p; p += NH * 2;
    unsigned short* Hp1 = (unsigned short*)p; p += NH * 2;
    unsigned short* Hp2 = (unsigned short*)p; p += NH * 2;
    unsigned short* WtAll = (unsigned short*)p; p += 4 * 16384 * 2;
    int* bcnt   = (int*)p; p += NBMAX * 4;     // [bcnt | S1a S2a S1b S2b] one memset
    float* S1a  = (float*)p; p += HF * 4;
    float* S2a  = (float*)p; p += HF * 4;
    float* S1b  = (float*)p; p += HF * 4;
    float* S2b  = (float*)p; p += HF * 4;
    float* scale = (float*)p; p += HF * 4;
    float* shift = (float*)p; p += HF * 4;
    float* partial = (float*)p; p += 1024 * 4;
    int* gstart = (int*)p; p += (Gn + 1) * 4;
    int* boff   = (int*)p; p += (NBMAX + 1) * 4;
    int* bcur   = (int*)p; p += NBMAX * 4;
    int* off    = (int*)p; p += (N + 1) * 4;
    int* esrc   = (int*)p; p += E * 4;
    unsigned* ebuf = (unsigned*)p; p += E * 4;

    unsigned short* Wt1a = WtAll;
    unsigned short* Wt1b = WtAll + 16384;
    unsigned short* Wt2a = WtAll + 32768;
    unsigned short* Wt2b = WtAll + 49152;

    float* out1 = (float*)d_out;
    float* out3 = out1 + (size_t)Gn * C_;
    float* outm = out3 + (size_t)Gn * D_;

    int nBlocks   = (N + 255) / 256;
    int castBlk   = ((int)(NH / 8) + 255) / 256;
    int gatherBlk = (N * 16 + 255) / 256;
    int gemmBlk   = (N + 63) / 64;
    const int BINB = 512;
    int chunk = (E + BINB - 1) / BINB;
    float invN = 1.0f / (float)N;

    // ---- casts + zero (bcnt + all BN stat arrays in one memset) + CSR ----
    cast_x<<<castBlk, 256, 0, stream>>>(x, xb, (int)(NH / 8));
    cast_wt<<<4, 256, 0, stream>>>(W1a, W1b, W2a, W2b, WtAll);
    hipMemsetAsync(bcnt, 0, NBMAX * 4 + 4 * HF * 4, stream);
    bucket_hist<<<BINB, 256, 0, stream>>>(dst, bcnt, E, NB, chunk);
    bucket_scan<<<1, 256, 0, stream>>>(bcnt, boff, bcur, NB);
    bucket_bin<<<BINB, 256, 0, stream>>>(src, dst, bcur, ebuf, E, NB, chunk);
    bucket_fill<<<NB, 256, 0, stream>>>(ebuf, boff, off, esrc, N, NB, E);
    graph_bounds<<<nBlocks, 256, 0, stream>>>(batch, gstart, N, Gn);

    // ---- layer 1 ----
    gather_u<false><<<gatherBlk, 256, 0, stream>>>(xb, off, esrc, eps1, nullptr, nullptr, U, N);
    gemm2r<<<gemmBlk, 256, 0, stream>>>(U, Wt1a, b1a, Wt1b, b1b, Hp1, S1a, S2a, N);
    bn_finalize<<<1, 128, 0, stream>>>(S1a, S2a, g1, be1, scale, shift, invN);

    // ---- layer 2 (BN1 folded into gather; BN2 folded into tail) ----
    gather_u<true><<<gatherBlk, 256, 0, stream>>>(Hp1, off, esrc, eps2, scale, shift, U, N);
    gemm2r<<<gemmBlk, 256, 0, stream>>>(U, Wt2a, b2a, Wt2b, b2b, Hp2, S1b, S2b, N);
    bn_finalize<<<1, 128, 0, stream>>>(S1b, S2b, g2, be2, scale, shift, invN);

    // ---- tail: pool + lin1 + mse + heads fused ----
    pool_tail<<<Gn, 512, 0, stream>>>(Hp2, scale, shift, gstart, Wlin1, blin1,
                                      Wloss, bloss, degree, Wlin2, blin2,
                                      Wlin4, blin4, out1, out3, partial, C_, D_);
    mse_final<<<1, 256, 0, stream>>>(partial, outm, invN, Gn);
}

// Round 9
// 531.516 us; speedup vs baseline: 1.0946x; 1.0300x over previous
//
#include <hip/hip_runtime.h>
#include <hip/hip_bf16.h>

#define HF 128   // feature/hidden dim (F == H == 128)
#define BSH 8    // bucket shift: 256 nodes per bucket
#define BSZ 256
#define NBMAX 1024
#define FCAP 8192
#define AST 136  // padded LDS row stride (bf16 elems)
#define HB 64    // histogram/bin blocks

typedef __attribute__((ext_vector_type(8))) short bf16x8;
typedef __attribute__((ext_vector_type(4))) float f32x4;

__device__ inline float bflo(unsigned u) { return __uint_as_float(u << 16); }
__device__ inline float bfhi(unsigned u) { return __uint_as_float(u & 0xffff0000u); }
__device__ inline unsigned short f2bf(float f) {
    unsigned u = __float_as_uint(f);
    unsigned r = (u + 0x7fffu + ((u >> 16) & 1u)) >> 16;
    return (unsigned short)r;
}
__device__ inline unsigned pack2(float a, float b) {
    return (unsigned)f2bf(a) | ((unsigned)f2bf(b) << 16);
}

// ============ mega-init: cast_x | cast_wt | hist partials | bounds | zero ====
__global__ __launch_bounds__(256) void init_all(
    const float* __restrict__ x, unsigned short* __restrict__ xb, int castBlk, int nchunks,
    const float* __restrict__ w0, const float* __restrict__ w1,
    const float* __restrict__ w2, const float* __restrict__ w3,
    unsigned short* __restrict__ WtAll,
    const int* __restrict__ dst, int* __restrict__ bpart, int E, int chunkH,
    const int* __restrict__ batch, int* __restrict__ gstart, int N, int Gn, int nBlocks,
    float* __restrict__ Szero, float* __restrict__ outm)
{
    __shared__ int lh[NBMAX];
    int b = blockIdx.x;
    int t = threadIdx.x;
    if (b < castBlk) {                       // ---- cast x -> bf16
        int i = b * 256 + t;
        if (i < nchunks) {
            float4 a = ((const float4*)x)[2 * i];
            float4 c = ((const float4*)x)[2 * i + 1];
            uint4 o;
            o.x = pack2(a.x, a.y); o.y = pack2(a.z, a.w);
            o.z = pack2(c.x, c.y); o.w = pack2(c.z, c.w);
            ((uint4*)xb)[i] = o;
        }
        return;
    }
    b -= castBlk;
    if (b < 4) {                             // ---- transpose-cast weights
        const float* W = (b == 0) ? w0 : (b == 1) ? w1 : (b == 2) ? w2 : w3;
        unsigned short* O = WtAll + b * 16384;
        for (int idx = t; idx < 16384; idx += 256) {
            int n = idx >> 7, k = idx & 127;
            O[idx] = f2bf(W[k * 128 + n]);
        }
        return;
    }
    b -= 4;
    if (b < HB) {                            // ---- histogram partials (no atomics, no memset)
        int NB = (N + BSZ - 1) >> BSH;
        for (int i = t; i < NB; i += 256) lh[i] = 0;
        __syncthreads();
        int beg = b * chunkH;
        int end = min(E, beg + chunkH);
        for (int e = beg + t; e < end; e += 256)
            atomicAdd(&lh[dst[e] >> BSH], 1);
        __syncthreads();
        for (int i = t; i < NB; i += 256) bpart[b * NBMAX + i] = lh[i];
        return;
    }
    b -= HB;
    if (b < nBlocks) {                       // ---- graph bounds
        int i = b * 256 + t;
        if (i >= N) return;
        int bi = batch[i];
        int bp = (i == 0) ? -1 : batch[i - 1];
        for (int g = bp + 1; g <= bi; g++) gstart[g] = i;
        if (i == N - 1)
            for (int g = bi + 1; g <= Gn; g++) gstart[g] = N;
        return;
    }
    // ---- zero BN stat arrays (4*HF floats) + mse output
    if (t < 2 * HF) { Szero[t] = 0.f; Szero[t + 2 * HF] = 0.f; }
    if (t == 0) outm[0] = 0.f;
}

// ============ scan: per-bucket totals + boff + in-place block prefixes ======
__global__ void scanp(int* __restrict__ bpart, int* __restrict__ boff, int NB, int E)
{
    __shared__ int tot[NBMAX];
    __shared__ int part[256];
    int t = threadIdx.x;
    for (int i = t; i < NB; i += 256) {
        int run = 0;
        for (int b = 0; b < HB; b++) {
            int v = bpart[b * NBMAX + i];
            bpart[b * NBMAX + i] = run;   // exclusive per-bucket block prefix
            run += v;
        }
        tot[i] = run;
    }
    __syncthreads();
    int v[4];
    int s = 0;
#pragma unroll
    for (int i = 0; i < 4; i++) {
        int idx = t * 4 + i;
        v[i] = (idx < NB) ? tot[idx] : 0;
        s += v[i];
    }
    part[t] = s;
    __syncthreads();
    for (int o = 1; o < 256; o <<= 1) {
        int y = (t >= o) ? part[t - o] : 0;
        __syncthreads();
        part[t] += y;
        __syncthreads();
    }
    int base = part[t] - s;
#pragma unroll
    for (int i = 0; i < 4; i++) {
        int idx = t * 4 + i;
        if (idx < NB) { boff[idx] = base; base += v[i]; }
    }
    if (t == 0) boff[NB] = E;
}

// ============ bin edges into bucket-contiguous ebuf (no global atomics) =====
__global__ __launch_bounds__(256) void bucket_bin(
    const int* __restrict__ src, const int* __restrict__ dst,
    const int* __restrict__ bpart, const int* __restrict__ boff,
    unsigned* __restrict__ ebuf, int E, int NB, int chunkH)
{
    __shared__ int lh[NBMAX];
    int hb = blockIdx.x;
    int t = threadIdx.x;
    for (int i = t; i < NB; i += 256) lh[i] = boff[i] + bpart[hb * NBMAX + i];
    __syncthreads();
    int beg = hb * chunkH;
    int end = min(E, beg + chunkH);
    for (int e = beg + t; e < end; e += 256) {
        int d = dst[e];
        int b = d >> BSH;
        int pos = atomicAdd(&lh[b], 1);
        ebuf[pos] = ((unsigned)src[e] << BSH) | (unsigned)(d & (BSZ - 1));
    }
}

// ============ per-bucket fill: off[] + sorted esrc, coalesced ================
__global__ __launch_bounds__(256) void bucket_fill(
    const unsigned* __restrict__ ebuf, const int* __restrict__ boff,
    int* __restrict__ off, int* __restrict__ esrc, int N, int NB, int E)
{
    __shared__ int deg[BSZ];
    __shared__ int pref[BSZ];
    __shared__ int lcur[BSZ];
    __shared__ int lsr[FCAP];
    int b = blockIdx.x;
    int t = threadIdx.x;
    int segBeg = boff[b], segEnd = boff[b + 1];
    int segLen = segEnd - segBeg;
    int node0 = b << BSH;
    deg[t] = 0;
    __syncthreads();
    for (int i = segBeg + t; i < segEnd; i += 256)
        atomicAdd(&deg[ebuf[i] & (BSZ - 1)], 1);
    __syncthreads();
    int dv = deg[t];
    pref[t] = dv;
    __syncthreads();
    for (int o = 1; o < 256; o <<= 1) {
        int y = (t >= o) ? pref[t - o] : 0;
        __syncthreads();
        pref[t] += y;
        __syncthreads();
    }
    int excl = pref[t] - dv;
    int node = node0 + t;
    if (node < N) off[node] = segBeg + excl;
    lcur[t] = excl;
    if (b == NB - 1 && t == 0) off[N] = E;
    __syncthreads();
    if (segLen <= FCAP) {
        for (int i = segBeg + t; i < segEnd; i += 256) {
            unsigned v = ebuf[i];
            int slot = atomicAdd(&lcur[v & (BSZ - 1)], 1);
            lsr[slot] = (int)(v >> BSH);
        }
        __syncthreads();
        for (int i = t; i < segLen; i += 256) esrc[segBeg + i] = lsr[i];
    } else {
        for (int i = segBeg + t; i < segEnd; i += 256) {
            unsigned v = ebuf[i];
            int slot = atomicAdd(&lcur[v & (BSZ - 1)], 1);
            esrc[segBeg + slot] = (int)(v >> BSH);
        }
    }
}

// ============ gather + fused U; FOLD computes BN1 scale/shift inline ========
template <bool FOLD>
__global__ __launch_bounds__(256) void gather_u(
    const unsigned short* __restrict__ xb, const int* __restrict__ off,
    const int* __restrict__ esrc, const float* __restrict__ epsp,
    const float* __restrict__ S1, const float* __restrict__ S2,
    const float* __restrict__ gamma, const float* __restrict__ beta, float invN,
    unsigned short* __restrict__ Uo, int N)
{
    __shared__ float lsc[HF], lsh[HF];
    int tid = threadIdx.x;
    if (FOLD) {
        if (tid < HF) {
            float mu = S1[tid] * invN;
            float var = S2[tid] * invN - mu * mu;
            float rs = rsqrtf(var + 1e-5f);
            float sc = gamma[tid] * rs;
            lsc[tid] = sc;
            lsh[tid] = beta[tid] - mu * sc;
        }
        __syncthreads();
    }
    int lane16 = tid & 15;
    int node = (blockIdx.x * 256 + tid) >> 4;
    if (node >= N) return;
    int beg = off[node], end = off[node + 1];
    float acc[8] = {0.f, 0.f, 0.f, 0.f, 0.f, 0.f, 0.f, 0.f};
    for (int j0 = beg; j0 < end; j0 += 16) {
        int myidx = (j0 + lane16 < end) ? esrc[j0 + lane16] : 0;
        int cnt = min(16, end - j0);
        for (int t = 0; t < cnt; t++) {
            int s = __shfl(myidx, t, 16);
            uint4 p = *(const uint4*)(xb + (size_t)s * HF + lane16 * 8);
            acc[0] += bflo(p.x); acc[1] += bfhi(p.x);
            acc[2] += bflo(p.y); acc[3] += bfhi(p.y);
            acc[4] += bflo(p.z); acc[5] += bfhi(p.z);
            acc[6] += bflo(p.w); acc[7] += bfhi(p.w);
        }
    }
    float ep = 1.0f + epsp[0];
    uint4 xx = *(const uint4*)(xb + (size_t)node * HF + lane16 * 8);
    acc[0] += ep * bflo(xx.x); acc[1] += ep * bfhi(xx.x);
    acc[2] += ep * bflo(xx.y); acc[3] += ep * bfhi(xx.y);
    acc[4] += ep * bflo(xx.z); acc[5] += ep * bfhi(xx.z);
    acc[6] += ep * bflo(xx.w); acc[7] += ep * bfhi(xx.w);
    if (FOLD) {
        float cf = ep + (float)(end - beg);
        const float4 s0 = *(const float4*)(&lsc[lane16 * 8]);
        const float4 s1 = *(const float4*)(&lsc[lane16 * 8 + 4]);
        const float4 h0 = *(const float4*)(&lsh[lane16 * 8]);
        const float4 h1 = *(const float4*)(&lsh[lane16 * 8 + 4]);
        acc[0] = acc[0] * s0.x + h0.x * cf; acc[1] = acc[1] * s0.y + h0.y * cf;
        acc[2] = acc[2] * s0.z + h0.z * cf; acc[3] = acc[3] * s0.w + h0.w * cf;
        acc[4] = acc[4] * s1.x + h1.x * cf; acc[5] = acc[5] * s1.y + h1.y * cf;
        acc[6] = acc[6] * s1.z + h1.z * cf; acc[7] = acc[7] * s1.w + h1.w * cf;
    }
    uint4 o;
    o.x = pack2(acc[0], acc[1]); o.y = pack2(acc[2], acc[3]);
    o.z = pack2(acc[4], acc[5]); o.w = pack2(acc[6], acc[7]);
    *(uint4*)(Uo + (size_t)node * HF + lane16 * 8) = o;
}

// ====== double-GEMM, LDS-staged W, wave-private row tiles ======
// Wave = 16 rows x 128 cols. Wa->lW (barrier), stage1 MFMA, T->lT (own rows,
// no barrier), barrier, Wb->lW, barrier, stage2 MFMA, epilogue w/ stats.
__global__ __launch_bounds__(256) void gemm2L(
    const unsigned short* __restrict__ U,
    const unsigned short* __restrict__ Wta, const float* __restrict__ ba,
    const unsigned short* __restrict__ Wtb, const float* __restrict__ bb,
    unsigned short* __restrict__ out, float* __restrict__ S1, float* __restrict__ S2,
    int n)
{
    __shared__ unsigned short lW[128 * AST];
    __shared__ unsigned short lT[64 * AST];
    __shared__ float lS1[HF], lS2[HF];
    int tid = threadIdx.x;
    int w = tid >> 6, lane = tid & 63;
    int m = lane & 15, quad = lane >> 4;
    int row0 = blockIdx.x * 64;
    if (tid < HF) { lS1[tid] = 0.f; lS2[tid] = 0.f; }

    for (int c = tid; c < 2048; c += 256) {       // Wa -> lW
        int r = c >> 4, k16 = c & 15;
        *(uint4*)(&lW[r * AST + k16 * 8]) = *(const uint4*)(Wta + r * HF + k16 * 8);
    }
    __syncthreads();

    int arow = row0 + w * 16 + m;
    if (arow >= n) arow = n - 1;                  // clamp; guarded below
    bf16x8 aF[4];
#pragma unroll
    for (int kk = 0; kk < 4; kk++)
        aF[kk] = *(const bf16x8*)(U + (size_t)arow * HF + kk * 32 + quad * 8);

    f32x4 acc[8];
#pragma unroll
    for (int nt = 0; nt < 8; nt++) acc[nt] = (f32x4){0.f, 0.f, 0.f, 0.f};
#pragma unroll
    for (int nt = 0; nt < 8; nt++) {
#pragma unroll
        for (int kk = 0; kk < 4; kk++) {
            bf16x8 b = *(const bf16x8*)(&lW[(nt * 16 + m) * AST + kk * 32 + quad * 8]);
            acc[nt] = __builtin_amdgcn_mfma_f32_16x16x32_bf16(aF[kk], b, acc[nt], 0, 0, 0);
        }
    }
    // T = relu(acc+ba) -> lT own rows
#pragma unroll
    for (int nt = 0; nt < 8; nt++) {
        float bav = ba[nt * 16 + m];
#pragma unroll
        for (int r = 0; r < 4; r++) {
            int lrow = w * 16 + quad * 4 + r;
            lT[lrow * AST + nt * 16 + m] = f2bf(fmaxf(acc[nt][r] + bav, 0.f));
        }
    }
    __syncthreads();                               // all waves done with lW (Wa)
    for (int c = tid; c < 2048; c += 256) {        // Wb -> lW
        int r = c >> 4, k16 = c & 15;
        *(uint4*)(&lW[r * AST + k16 * 8]) = *(const uint4*)(Wtb + r * HF + k16 * 8);
    }
    __syncthreads();

#pragma unroll
    for (int kk = 0; kk < 4; kk++)
        aF[kk] = *(const bf16x8*)(&lT[(w * 16 + m) * AST + kk * 32 + quad * 8]);
#pragma unroll
    for (int nt = 0; nt < 8; nt++) acc[nt] = (f32x4){0.f, 0.f, 0.f, 0.f};
#pragma unroll
    for (int nt = 0; nt < 8; nt++) {
#pragma unroll
        for (int kk = 0; kk < 4; kk++) {
            bf16x8 b = *(const bf16x8*)(&lW[(nt * 16 + m) * AST + kk * 32 + quad * 8]);
            acc[nt] = __builtin_amdgcn_mfma_f32_16x16x32_bf16(aF[kk], b, acc[nt], 0, 0, 0);
        }
    }
    // epilogue: relu + stats + C -> lT own rows, vectorized store
#pragma unroll
    for (int nt = 0; nt < 8; nt++) {
        int col = nt * 16 + m;
        float bbv = bb[col];
        float cs = 0.f, cq = 0.f;
#pragma unroll
        for (int r = 0; r < 4; r++) {
            int lrow = w * 16 + quad * 4 + r;
            int grow = row0 + lrow;
            float v = fmaxf(acc[nt][r] + bbv, 0.f);
            lT[lrow * AST + col] = f2bf(v);
            if (grow < n) { cs += v; cq += v * v; }
        }
        cs += __shfl_down(cs, 32); cs += __shfl_down(cs, 16);
        cq += __shfl_down(cq, 32); cq += __shfl_down(cq, 16);
        if (quad == 0) { atomicAdd(&lS1[col], cs); atomicAdd(&lS2[col], cq); }
    }
#pragma unroll
    for (int i = 0; i < 4; i++) {
        int idx = i * 64 + lane;
        int r = idx >> 4, k16 = idx & 15;
        int grow = row0 + w * 16 + r;
        if (grow < n)
            *(uint4*)(out + (size_t)grow * HF + k16 * 8) =
                *(const uint4*)(&lT[(w * 16 + r) * AST + k16 * 8]);
    }
    __syncthreads();
    if (tid < HF) { atomicAdd(&S1[tid], lS1[tid]); atomicAdd(&S2[tid], lS2[tid]); }
}

// ---- pool (BN2 inline) + lin1 + mse (atomic) + heads, one kernel/graph ----
__global__ __launch_bounds__(512) void pool_tail(
    const unsigned short* __restrict__ h2raw,
    const float* __restrict__ S1, const float* __restrict__ S2,
    const float* __restrict__ gamma, const float* __restrict__ beta, float invN,
    const int* __restrict__ gstart, const float* __restrict__ W,
    const float* __restrict__ bias,
    const float* __restrict__ Wloss, const float* __restrict__ blossp,
    const float* __restrict__ degree,
    const float* __restrict__ W2, const float* __restrict__ b2,
    const float* __restrict__ W4, const float* __restrict__ b4,
    float* __restrict__ out1, float* __restrict__ out3,
    float* __restrict__ outm, int C_, int D_)
{
    __shared__ float lsc[HF], lsh[HF];
    __shared__ float red[8][HF];
    __shared__ float gv[HF];
    __shared__ float part[4][HF];
    __shared__ float wred[8];
    __shared__ float zz[HF];
    __shared__ float logits[16];
    __shared__ float lse_s;
    int gid = blockIdx.x;
    int t = threadIdx.x;
    if (t < HF) {
        float mu = S1[t] * invN;
        float var = S2[t] * invN - mu * mu;
        float rs = rsqrtf(var + 1e-5f);
        float sc = gamma[t] * rs;
        lsc[t] = sc;
        lsh[t] = beta[t] - mu * sc;
    }
    __syncthreads();
    int c2 = t & 63;
    int rg = t >> 6;
    int b = gstart[gid], e = gstart[gid + 1];
    float wla = lsc[2 * c2] * Wloss[2 * c2];
    float wlb = lsc[2 * c2 + 1] * Wloss[2 * c2 + 1];
    float c0l = lsh[2 * c2] * Wloss[2 * c2] + lsh[2 * c2 + 1] * Wloss[2 * c2 + 1];
    float bl = blossp[0];
    float s0 = 0.f, s1 = 0.f, macc = 0.f;
    for (int r = b + rg; r < e; r += 8) {
        unsigned u = *(const unsigned*)(h2raw + (size_t)r * HF + c2 * 2);
        float v0 = bflo(u), v1 = bfhi(u);
        s0 += v0; s1 += v1;
        float m = v0 * wla + v1 * wlb + c0l;
#pragma unroll
        for (int o = 32; o > 0; o >>= 1) m += __shfl_down(m, o);
        if (c2 == 0) {
            float d = m + bl - degree[r];
            macc += d * d;
        }
    }
    red[rg][c2 * 2] = s0;
    red[rg][c2 * 2 + 1] = s1;
    if (c2 == 0) wred[rg] = macc;
    __syncthreads();
    if (t < HF) {
        float s = red[0][t] + red[1][t] + red[2][t] + red[3][t]
                + red[4][t] + red[5][t] + red[6][t] + red[7][t];
        gv[t] = (e > b) ? lsc[t] * (s / (float)(e - b)) + lsh[t] : 0.f;
    }
    __syncthreads();
    int c = t & 127, kg = t >> 7;
    float a = 0.f;
#pragma unroll 8
    for (int k = kg * 32; k < kg * 32 + 32; k++) a += gv[k] * W[(size_t)k * HF + c];
    part[kg][c] = a;
    __syncthreads();
    if (t < HF) {
        float aa = part[0][t] + part[1][t] + part[2][t] + part[3][t] + bias[t];
        zz[t] = fmaxf(aa, 0.f);
    }
    if (t == 0) {
        float ps = wred[0] + wred[1] + wred[2] + wred[3]
                 + wred[4] + wred[5] + wred[6] + wred[7];
        atomicAdd(outm, ps * invN);
    }
    __syncthreads();
    if (t < C_) {
        float aa = b2[t];
        for (int k = 0; k < HF; k++) aa += zz[k] * W2[(size_t)k * C_ + t];
        logits[t] = aa;
    }
    __syncthreads();
    if (t == 0) {
        float mx = -1e30f;
        for (int i = 0; i < C_; i++) mx = fmaxf(mx, logits[i]);
        float s = 0.f;
        for (int i = 0; i < C_; i++) s += expf(logits[i] - mx);
        lse_s = mx + logf(s);
    }
    __syncthreads();
    if (t < C_) out1[(size_t)gid * C_ + t] = logits[t] - lse_s;
    if (t < D_) {
        float aa = b4[t];
        for (int k = 0; k < HF; k++) aa += zz[k] * W4[(size_t)k * D_ + t];
        out3[(size_t)gid * D_ + t] = aa;
    }
}

extern "C" void kernel_launch(void* const* d_in, const int* in_sizes, int n_in,
                              void* d_out, int out_size, void* d_ws, size_t ws_size,
                              hipStream_t stream)
{
    const float* x      = (const float*)d_in[0];
    const int*   ei     = (const int*)d_in[1];
    const int*   batch  = (const int*)d_in[2];
    const float* degree = (const float*)d_in[3];
    const float* eps1   = (const float*)d_in[4];
    const float* W1a    = (const float*)d_in[5];
    const float* b1a    = (const float*)d_in[6];
    const float* W1b    = (const float*)d_in[7];
    const float* b1b    = (const float*)d_in[8];
    const float* g1     = (const float*)d_in[9];
    const float* be1    = (const float*)d_in[10];
    const float* eps2   = (const float*)d_in[11];
    const float* W2a    = (const float*)d_in[12];
    const float* b2a    = (const float*)d_in[13];
    const float* W2b    = (const float*)d_in[14];
    const float* b2b    = (const float*)d_in[15];
    const float* g2     = (const float*)d_in[16];
    const float* be2    = (const float*)d_in[17];
    const float* Wlin1  = (const float*)d_in[18];
    const float* blin1  = (const float*)d_in[19];
    const float* Wlin2  = (const float*)d_in[20];
    const float* blin2  = (const float*)d_in[21];
    const float* Wlin4  = (const float*)d_in[22];
    const float* blin4  = (const float*)d_in[23];
    const float* Wloss  = (const float*)d_in[24];
    const float* bloss  = (const float*)d_in[25];

    const int N  = in_sizes[0] / HF;
    const int E  = in_sizes[1] / 2;
    const int C_ = in_sizes[21];
    const int D_ = in_sizes[23];
    const int Gn = (out_size - 1) / (C_ + D_);
    const int NB = (N + BSZ - 1) >> BSH;

    const int* src = ei;
    const int* dst = ei + E;

    size_t NH = (size_t)N * HF;
    char* p = (char*)d_ws;
    unsigned short* xb  = (unsigned short*)p; p += NH * 2;
    unsigned short* U   = (unsigned short*)p; p += NH * 2;
    unsigned short* Hp1 = (unsigned short*)p; p += NH * 2;
    unsigned short* Hp2 = (unsigned short*)p; p += NH * 2;
    unsigned short* WtAll = (unsigned short*)p; p += 4 * 16384 * 2;
    float* S1a  = (float*)p; p += HF * 4;     // [S1a S2a S1b S2b] contiguous
    float* S2a  = (float*)p; p += HF * 4;
    float* S1b  = (float*)p; p += HF * 4;
    float* S2b  = (float*)p; p += HF * 4;
    int* gstart = (int*)p; p += (Gn + 1) * 4;
    int* boff   = (int*)p; p += (NBMAX + 1) * 4;
    int* bpart  = (int*)p; p += HB * NBMAX * 4;
    int* off    = (int*)p; p += (N + 1) * 4;
    int* esrc   = (int*)p; p += E * 4;
    unsigned* ebuf = (unsigned*)p; p += E * 4;

    unsigned short* Wt1a = WtAll;
    unsigned short* Wt1b = WtAll + 16384;
    unsigned short* Wt2a = WtAll + 32768;
    unsigned short* Wt2b = WtAll + 49152;

    float* out1 = (float*)d_out;
    float* out3 = out1 + (size_t)Gn * C_;
    float* outm = out3 + (size_t)Gn * D_;

    int nchunks  = (int)(NH / 8);
    int castBlk  = (nchunks + 255) / 256;
    int nBlocks  = (N + 255) / 256;
    int gatherBlk = (N * 16 + 255) / 256;
    int gemmBlk  = (N + 63) / 64;
    int chunkH   = (E + HB - 1) / HB;
    float invN = 1.0f / (float)N;

    int initBlk = castBlk + 4 + HB + nBlocks + 1;

    // 1. mega-init: cast x, cast W, hist partials, graph bounds, zero stats+mse
    init_all<<<initBlk, 256, 0, stream>>>(x, xb, castBlk, nchunks,
                                          W1a, W1b, W2a, W2b, WtAll,
                                          dst, bpart, E, chunkH,
                                          batch, gstart, N, Gn, nBlocks,
                                          S1a, outm);
    // 2. bucket offsets + per-block bases
    scanp<<<1, 256, 0, stream>>>(bpart, boff, NB, E);
    // 3. bin edges (no global atomics)
    bucket_bin<<<HB, 256, 0, stream>>>(src, dst, bpart, boff, ebuf, E, NB, chunkH);
    // 4. per-bucket CSR fill
    bucket_fill<<<NB, 256, 0, stream>>>(ebuf, boff, off, esrc, N, NB, E);
    // 5-6. layer 1
    gather_u<false><<<gatherBlk, 256, 0, stream>>>(xb, off, esrc, eps1,
                                                   nullptr, nullptr, nullptr, nullptr, 0.f, U, N);
    gemm2L<<<gemmBlk, 256, 0, stream>>>(U, Wt1a, b1a, Wt1b, b1b, Hp1, S1a, S2a, N);
    // 7-8. layer 2 (BN1 finalize inline in gather)
    gather_u<true><<<gatherBlk, 256, 0, stream>>>(Hp1, off, esrc, eps2,
                                                  S1a, S2a, g1, be1, invN, U, N);
    gemm2L<<<gemmBlk, 256, 0, stream>>>(U, Wt2a, b2a, Wt2b, b2b, Hp2, S1b, S2b, N);
    // 9. tail: BN2 finalize inline + pool + lin1 + mse atomic + heads
    pool_tail<<<Gn, 512, 0, stream>>>(Hp2, S1b, S2b, g2, be2, invN, gstart,
                                      Wlin1, blin1, Wloss, bloss, degree,
                                      Wlin2, blin2, Wlin4, blin4,
                                      out1, out3, outm, C_, D_);
}

// Round 10
// 492.469 us; speedup vs baseline: 1.1814x; 1.0793x over previous
//
#include <hip/hip_runtime.h>
#include <hip/hip_bf16.h>

#define HF 128   // feature/hidden dim (F == H == 128)
#define BSH 8    // bucket shift: 256 nodes per bucket
#define BSZ 256
#define NBMAX 1024
#define FCAP 8192
#define AST 136  // padded LDS row stride (bf16 elems)
#define HB 512   // histogram/bin blocks (512: proven occupancy for bin)

typedef __attribute__((ext_vector_type(8))) short bf16x8;
typedef __attribute__((ext_vector_type(4))) float f32x4;

__device__ inline float bflo(unsigned u) { return __uint_as_float(u << 16); }
__device__ inline float bfhi(unsigned u) { return __uint_as_float(u & 0xffff0000u); }
__device__ inline unsigned short f2bf(float f) {
    unsigned u = __float_as_uint(f);
    unsigned r = (u + 0x7fffu + ((u >> 16) & 1u)) >> 16;
    return (unsigned short)r;
}
__device__ inline unsigned pack2(float a, float b) {
    return (unsigned)f2bf(a) | ((unsigned)f2bf(b) << 16);
}

// ============ mega-init: cast_x | cast_wt | hist partials | bounds | zero ====
__global__ __launch_bounds__(256) void init_all(
    const float* __restrict__ x, unsigned short* __restrict__ xb, int castBlk, int nchunks,
    const float* __restrict__ w0, const float* __restrict__ w1,
    const float* __restrict__ w2, const float* __restrict__ w3,
    unsigned short* __restrict__ WtAll,
    const int* __restrict__ dst, int* __restrict__ bpart, int E, int chunkH,
    const int* __restrict__ batch, int* __restrict__ gstart, int N, int Gn, int nBlocks,
    float* __restrict__ Szero, float* __restrict__ outm)
{
    __shared__ int lh[NBMAX];
    int b = blockIdx.x;
    int t = threadIdx.x;
    if (b < castBlk) {                       // ---- cast x -> bf16
        int i = b * 256 + t;
        if (i < nchunks) {
            float4 a = ((const float4*)x)[2 * i];
            float4 c = ((const float4*)x)[2 * i + 1];
            uint4 o;
            o.x = pack2(a.x, a.y); o.y = pack2(a.z, a.w);
            o.z = pack2(c.x, c.y); o.w = pack2(c.z, c.w);
            ((uint4*)xb)[i] = o;
        }
        return;
    }
    b -= castBlk;
    if (b < 4) {                             // ---- transpose-cast weights
        const float* W = (b == 0) ? w0 : (b == 1) ? w1 : (b == 2) ? w2 : w3;
        unsigned short* O = WtAll + b * 16384;
        for (int idx = t; idx < 16384; idx += 256) {
            int n = idx >> 7, k = idx & 127;
            O[idx] = f2bf(W[k * 128 + n]);
        }
        return;
    }
    b -= 4;
    if (b < HB) {                            // ---- histogram partials (transposed write)
        int NBl = (N + BSZ - 1) >> BSH;
        for (int i = t; i < NBl; i += 256) lh[i] = 0;
        __syncthreads();
        int beg = b * chunkH;
        int end = min(E, beg + chunkH);
        for (int e = beg + t; e < end; e += 256)
            atomicAdd(&lh[dst[e] >> BSH], 1);
        __syncthreads();
        for (int i = t; i < NBl; i += 256) bpart[i * HB + b] = lh[i];
        return;
    }
    b -= HB;
    if (b < nBlocks) {                       // ---- graph bounds
        int i = b * 256 + t;
        if (i >= N) return;
        int bi = batch[i];
        int bp = (i == 0) ? -1 : batch[i - 1];
        for (int g = bp + 1; g <= bi; g++) gstart[g] = i;
        if (i == N - 1)
            for (int g = bi + 1; g <= Gn; g++) gstart[g] = N;
        return;
    }
    // ---- zero BN stat arrays (4*HF floats) + mse output
    if (t < 2 * HF) { Szero[t] = 0.f; Szero[t + 2 * HF] = 0.f; }
    if (t == 0) outm[0] = 0.f;
}

// ============ scan: bucket totals (int4 over contiguous partials) + boff/bcur
__global__ void scanp(const int* __restrict__ bpart, int* __restrict__ boff,
                      int* __restrict__ bcur, int NB, int E)
{
    __shared__ int tot[NBMAX];
    __shared__ int part[256];
    int t = threadIdx.x;
    for (int i = t; i < NB; i += 256) {
        const int4* pp = (const int4*)(bpart + (size_t)i * HB);
        int run = 0;
#pragma unroll 4
        for (int b = 0; b < HB / 4; b++) {
            int4 v = pp[b];
            run += v.x + v.y + v.z + v.w;
        }
        tot[i] = run;
    }
    __syncthreads();
    int v[4];
    int s = 0;
#pragma unroll
    for (int i = 0; i < 4; i++) {
        int idx = t * 4 + i;
        v[i] = (idx < NB) ? tot[idx] : 0;
        s += v[i];
    }
    part[t] = s;
    __syncthreads();
    for (int o = 1; o < 256; o <<= 1) {
        int y = (t >= o) ? part[t - o] : 0;
        __syncthreads();
        part[t] += y;
        __syncthreads();
    }
    int base = part[t] - s;
#pragma unroll
    for (int i = 0; i < 4; i++) {
        int idx = t * 4 + i;
        if (idx < NB) { boff[idx] = base; bcur[idx] = base; base += v[i]; }
    }
    if (t == 0) boff[NB] = E;
}

// ============ bin edges: LDS hist -> global chunk reservation -> scatter ====
__global__ __launch_bounds__(256) void bucket_bin(
    const int* __restrict__ src, const int* __restrict__ dst,
    int* __restrict__ bcur, unsigned* __restrict__ ebuf, int E, int NB, int chunkH)
{
    __shared__ int lh[NBMAX];
    int t = threadIdx.x;
    for (int i = t; i < NB; i += 256) lh[i] = 0;
    __syncthreads();
    int beg = blockIdx.x * chunkH;
    int end = min(E, beg + chunkH);
    for (int e = beg + t; e < end; e += 256)
        atomicAdd(&lh[dst[e] >> BSH], 1);
    __syncthreads();
    for (int i = t; i < NB; i += 256) {
        int c = lh[i];
        lh[i] = c ? atomicAdd(&bcur[i], c) : 0;
    }
    __syncthreads();
    for (int e = beg + t; e < end; e += 256) {
        int d = dst[e];
        int b = d >> BSH;
        int pos = atomicAdd(&lh[b], 1);
        ebuf[pos] = ((unsigned)src[e] << BSH) | (unsigned)(d & (BSZ - 1));
    }
}

// ============ per-bucket fill: off[] + sorted esrc, coalesced ================
__global__ __launch_bounds__(256) void bucket_fill(
    const unsigned* __restrict__ ebuf, const int* __restrict__ boff,
    int* __restrict__ off, int* __restrict__ esrc, int N, int NB, int E)
{
    __shared__ int deg[BSZ];
    __shared__ int pref[BSZ];
    __shared__ int lcur[BSZ];
    __shared__ int lsr[FCAP];
    int b = blockIdx.x;
    int t = threadIdx.x;
    int segBeg = boff[b], segEnd = boff[b + 1];
    int segLen = segEnd - segBeg;
    int node0 = b << BSH;
    deg[t] = 0;
    __syncthreads();
    for (int i = segBeg + t; i < segEnd; i += 256)
        atomicAdd(&deg[ebuf[i] & (BSZ - 1)], 1);
    __syncthreads();
    int dv = deg[t];
    pref[t] = dv;
    __syncthreads();
    for (int o = 1; o < 256; o <<= 1) {
        int y = (t >= o) ? pref[t - o] : 0;
        __syncthreads();
        pref[t] += y;
        __syncthreads();
    }
    int excl = pref[t] - dv;
    int node = node0 + t;
    if (node < N) off[node] = segBeg + excl;
    lcur[t] = excl;
    if (b == NB - 1 && t == 0) off[N] = E;
    __syncthreads();
    if (segLen <= FCAP) {
        for (int i = segBeg + t; i < segEnd; i += 256) {
            unsigned v = ebuf[i];
            int slot = atomicAdd(&lcur[v & (BSZ - 1)], 1);
            lsr[slot] = (int)(v >> BSH);
        }
        __syncthreads();
        for (int i = t; i < segLen; i += 256) esrc[segBeg + i] = lsr[i];
    } else {
        for (int i = segBeg + t; i < segEnd; i += 256) {
            unsigned v = ebuf[i];
            int slot = atomicAdd(&lcur[v & (BSZ - 1)], 1);
            esrc[segBeg + slot] = (int)(v >> BSH);
        }
    }
}

// ============ gather + fused U; FOLD computes BN1 scale/shift inline ========
template <bool FOLD>
__global__ __launch_bounds__(256) void gather_u(
    const unsigned short* __restrict__ xb, const int* __restrict__ off,
    const int* __restrict__ esrc, const float* __restrict__ epsp,
    const float* __restrict__ S1, const float* __restrict__ S2,
    const float* __restrict__ gamma, const float* __restrict__ beta, float invN,
    unsigned short* __restrict__ Uo, int N)
{
    __shared__ float lsc[HF], lsh[HF];
    int tid = threadIdx.x;
    if (FOLD) {
        if (tid < HF) {
            float mu = S1[tid] * invN;
            float var = S2[tid] * invN - mu * mu;
            float rs = rsqrtf(var + 1e-5f);
            float sc = gamma[tid] * rs;
            lsc[tid] = sc;
            lsh[tid] = beta[tid] - mu * sc;
        }
        __syncthreads();
    }
    int lane16 = tid & 15;
    int node = (blockIdx.x * 256 + tid) >> 4;
    if (node >= N) return;
    int beg = off[node], end = off[node + 1];
    float acc[8] = {0.f, 0.f, 0.f, 0.f, 0.f, 0.f, 0.f, 0.f};
    for (int j0 = beg; j0 < end; j0 += 16) {
        int myidx = (j0 + lane16 < end) ? esrc[j0 + lane16] : 0;
        int cnt = min(16, end - j0);
        for (int t = 0; t < cnt; t++) {
            int s = __shfl(myidx, t, 16);
            uint4 p = *(const uint4*)(xb + (size_t)s * HF + lane16 * 8);
            acc[0] += bflo(p.x); acc[1] += bfhi(p.x);
            acc[2] += bflo(p.y); acc[3] += bfhi(p.y);
            acc[4] += bflo(p.z); acc[5] += bfhi(p.z);
            acc[6] += bflo(p.w); acc[7] += bfhi(p.w);
        }
    }
    float ep = 1.0f + epsp[0];
    uint4 xx = *(const uint4*)(xb + (size_t)node * HF + lane16 * 8);
    acc[0] += ep * bflo(xx.x); acc[1] += ep * bfhi(xx.x);
    acc[2] += ep * bflo(xx.y); acc[3] += ep * bfhi(xx.y);
    acc[4] += ep * bflo(xx.z); acc[5] += ep * bfhi(xx.z);
    acc[6] += ep * bflo(xx.w); acc[7] += ep * bfhi(xx.w);
    if (FOLD) {
        float cf = ep + (float)(end - beg);
        const float4 s0 = *(const float4*)(&lsc[lane16 * 8]);
        const float4 s1 = *(const float4*)(&lsc[lane16 * 8 + 4]);
        const float4 h0 = *(const float4*)(&lsh[lane16 * 8]);
        const float4 h1 = *(const float4*)(&lsh[lane16 * 8 + 4]);
        acc[0] = acc[0] * s0.x + h0.x * cf; acc[1] = acc[1] * s0.y + h0.y * cf;
        acc[2] = acc[2] * s0.z + h0.z * cf; acc[3] = acc[3] * s0.w + h0.w * cf;
        acc[4] = acc[4] * s1.x + h1.x * cf; acc[5] = acc[5] * s1.y + h1.y * cf;
        acc[6] = acc[6] * s1.z + h1.z * cf; acc[7] = acc[7] * s1.w + h1.w * cf;
    }
    uint4 o;
    o.x = pack2(acc[0], acc[1]); o.y = pack2(acc[2], acc[3]);
    o.z = pack2(acc[4], acc[5]); o.w = pack2(acc[6], acc[7]);
    *(uint4*)(Uo + (size_t)node * HF + lane16 * 8) = o;
}

// ====== double-GEMM, LDS-staged W, wave-private row tiles ======
__global__ __launch_bounds__(256) void gemm2L(
    const unsigned short* __restrict__ U,
    const unsigned short* __restrict__ Wta, const float* __restrict__ ba,
    const unsigned short* __restrict__ Wtb, const float* __restrict__ bb,
    unsigned short* __restrict__ out, float* __restrict__ S1, float* __restrict__ S2,
    int n)
{
    __shared__ unsigned short lW[128 * AST];
    __shared__ unsigned short lT[64 * AST];
    __shared__ float lS1[HF], lS2[HF];
    int tid = threadIdx.x;
    int w = tid >> 6, lane = tid & 63;
    int m = lane & 15, quad = lane >> 4;
    int row0 = blockIdx.x * 64;
    if (tid < HF) { lS1[tid] = 0.f; lS2[tid] = 0.f; }

    for (int c = tid; c < 2048; c += 256) {       // Wa -> lW
        int r = c >> 4, k16 = c & 15;
        *(uint4*)(&lW[r * AST + k16 * 8]) = *(const uint4*)(Wta + r * HF + k16 * 8);
    }
    __syncthreads();

    int arow = row0 + w * 16 + m;
    if (arow >= n) arow = n - 1;                  // clamp; guarded below
    bf16x8 aF[4];
#pragma unroll
    for (int kk = 0; kk < 4; kk++)
        aF[kk] = *(const bf16x8*)(U + (size_t)arow * HF + kk * 32 + quad * 8);

    f32x4 acc[8];
#pragma unroll
    for (int nt = 0; nt < 8; nt++) acc[nt] = (f32x4){0.f, 0.f, 0.f, 0.f};
#pragma unroll
    for (int nt = 0; nt < 8; nt++) {
#pragma unroll
        for (int kk = 0; kk < 4; kk++) {
            bf16x8 b = *(const bf16x8*)(&lW[(nt * 16 + m) * AST + kk * 32 + quad * 8]);
            acc[nt] = __builtin_amdgcn_mfma_f32_16x16x32_bf16(aF[kk], b, acc[nt], 0, 0, 0);
        }
    }
    // T = relu(acc+ba) -> lT own rows
#pragma unroll
    for (int nt = 0; nt < 8; nt++) {
        float bav = ba[nt * 16 + m];
#pragma unroll
        for (int r = 0; r < 4; r++) {
            int lrow = w * 16 + quad * 4 + r;
            lT[lrow * AST + nt * 16 + m] = f2bf(fmaxf(acc[nt][r] + bav, 0.f));
        }
    }
    __syncthreads();                               // all waves done with lW (Wa)
    for (int c = tid; c < 2048; c += 256) {        // Wb -> lW
        int r = c >> 4, k16 = c & 15;
        *(uint4*)(&lW[r * AST + k16 * 8]) = *(const uint4*)(Wtb + r * HF + k16 * 8);
    }
    __syncthreads();

#pragma unroll
    for (int kk = 0; kk < 4; kk++)
        aF[kk] = *(const bf16x8*)(&lT[(w * 16 + m) * AST + kk * 32 + quad * 8]);
#pragma unroll
    for (int nt = 0; nt < 8; nt++) acc[nt] = (f32x4){0.f, 0.f, 0.f, 0.f};
#pragma unroll
    for (int nt = 0; nt < 8; nt++) {
#pragma unroll
        for (int kk = 0; kk < 4; kk++) {
            bf16x8 b = *(const bf16x8*)(&lW[(nt * 16 + m) * AST + kk * 32 + quad * 8]);
            acc[nt] = __builtin_amdgcn_mfma_f32_16x16x32_bf16(aF[kk], b, acc[nt], 0, 0, 0);
        }
    }
    // epilogue: relu + stats + C -> lT own rows, vectorized store
#pragma unroll
    for (int nt = 0; nt < 8; nt++) {
        int col = nt * 16 + m;
        float bbv = bb[col];
        float cs = 0.f, cq = 0.f;
#pragma unroll
        for (int r = 0; r < 4; r++) {
            int lrow = w * 16 + quad * 4 + r;
            int grow = row0 + lrow;
            float v = fmaxf(acc[nt][r] + bbv, 0.f);
            lT[lrow * AST + col] = f2bf(v);
            if (grow < n) { cs += v; cq += v * v; }
        }
        cs += __shfl_down(cs, 32); cs += __shfl_down(cs, 16);
        cq += __shfl_down(cq, 32); cq += __shfl_down(cq, 16);
        if (quad == 0) { atomicAdd(&lS1[col], cs); atomicAdd(&lS2[col], cq); }
    }
#pragma unroll
    for (int i = 0; i < 4; i++) {
        int idx = i * 64 + lane;
        int r = idx >> 4, k16 = idx & 15;
        int grow = row0 + w * 16 + r;
        if (grow < n)
            *(uint4*)(out + (size_t)grow * HF + k16 * 8) =
                *(const uint4*)(&lT[(w * 16 + r) * AST + k16 * 8]);
    }
    __syncthreads();
    if (tid < HF) { atomicAdd(&S1[tid], lS1[tid]); atomicAdd(&S2[tid], lS2[tid]); }
}

// ---- pool (BN2 inline) + lin1 + mse (atomic) + heads, one kernel/graph ----
__global__ __launch_bounds__(512) void pool_tail(
    const unsigned short* __restrict__ h2raw,
    const float* __restrict__ S1, const float* __restrict__ S2,
    const float* __restrict__ gamma, const float* __restrict__ beta, float invN,
    const int* __restrict__ gstart, const float* __restrict__ W,
    const float* __restrict__ bias,
    const float* __restrict__ Wloss, const float* __restrict__ blossp,
    const float* __restrict__ degree,
    const float* __restrict__ W2, const float* __restrict__ b2,
    const float* __restrict__ W4, const float* __restrict__ b4,
    float* __restrict__ out1, float* __restrict__ out3,
    float* __restrict__ outm, int C_, int D_)
{
    __shared__ float lsc[HF], lsh[HF];
    __shared__ float red[8][HF];
    __shared__ float gv[HF];
    __shared__ float part[4][HF];
    __shared__ float wred[8];
    __shared__ float zz[HF];
    __shared__ float logits[16];
    __shared__ float lse_s;
    int gid = blockIdx.x;
    int t = threadIdx.x;
    if (t < HF) {
        float mu = S1[t] * invN;
        float var = S2[t] * invN - mu * mu;
        float rs = rsqrtf(var + 1e-5f);
        float sc = gamma[t] * rs;
        lsc[t] = sc;
        lsh[t] = beta[t] - mu * sc;
    }
    __syncthreads();
    int c2 = t & 63;
    int rg = t >> 6;
    int b = gstart[gid], e = gstart[gid + 1];
    float wla = lsc[2 * c2] * Wloss[2 * c2];
    float wlb = lsc[2 * c2 + 1] * Wloss[2 * c2 + 1];
    float c0l = lsh[2 * c2] * Wloss[2 * c2] + lsh[2 * c2 + 1] * Wloss[2 * c2 + 1];
    float bl = blossp[0];
    float s0 = 0.f, s1 = 0.f, macc = 0.f;
    for (int r = b + rg; r < e; r += 8) {
        unsigned u = *(const unsigned*)(h2raw + (size_t)r * HF + c2 * 2);
        float v0 = bflo(u), v1 = bfhi(u);
        s0 += v0; s1 += v1;
        float m = v0 * wla + v1 * wlb + c0l;
#pragma unroll
        for (int o = 32; o > 0; o >>= 1) m += __shfl_down(m, o);
        if (c2 == 0) {
            float d = m + bl - degree[r];
            macc += d * d;
        }
    }
    red[rg][c2 * 2] = s0;
    red[rg][c2 * 2 + 1] = s1;
    if (c2 == 0) wred[rg] = macc;
    __syncthreads();
    if (t < HF) {
        float s = red[0][t] + red[1][t] + red[2][t] + red[3][t]
                + red[4][t] + red[5][t] + red[6][t] + red[7][t];
        gv[t] = (e > b) ? lsc[t] * (s / (float)(e - b)) + lsh[t] : 0.f;
    }
    __syncthreads();
    int c = t & 127, kg = t >> 7;
    float a = 0.f;
#pragma unroll 8
    for (int k = kg * 32; k < kg * 32 + 32; k++) a += gv[k] * W[(size_t)k * HF + c];
    part[kg][c] = a;
    __syncthreads();
    if (t < HF) {
        float aa = part[0][t] + part[1][t] + part[2][t] + part[3][t] + bias[t];
        zz[t] = fmaxf(aa, 0.f);
    }
    if (t == 0) {
        float ps = wred[0] + wred[1] + wred[2] + wred[3]
                 + wred[4] + wred[5] + wred[6] + wred[7];
        atomicAdd(outm, ps * invN);
    }
    __syncthreads();
    if (t < C_) {
        float aa = b2[t];
        for (int k = 0; k < HF; k++) aa += zz[k] * W2[(size_t)k * C_ + t];
        logits[t] = aa;
    }
    __syncthreads();
    if (t == 0) {
        float mx = -1e30f;
        for (int i = 0; i < C_; i++) mx = fmaxf(mx, logits[i]);
        float s = 0.f;
        for (int i = 0; i < C_; i++) s += expf(logits[i] - mx);
        lse_s = mx + logf(s);
    }
    __syncthreads();
    if (t < C_) out1[(size_t)gid * C_ + t] = logits[t] - lse_s;
    if (t < D_) {
        float aa = b4[t];
        for (int k = 0; k < HF; k++) aa += zz[k] * W4[(size_t)k * D_ + t];
        out3[(size_t)gid * D_ + t] = aa;
    }
}

extern "C" void kernel_launch(void* const* d_in, const int* in_sizes, int n_in,
                              void* d_out, int out_size, void* d_ws, size_t ws_size,
                              hipStream_t stream)
{
    const float* x      = (const float*)d_in[0];
    const int*   ei     = (const int*)d_in[1];
    const int*   batch  = (const int*)d_in[2];
    const float* degree = (const float*)d_in[3];
    const float* eps1   = (const float*)d_in[4];
    const float* W1a    = (const float*)d_in[5];
    const float* b1a    = (const float*)d_in[6];
    const float* W1b    = (const float*)d_in[7];
    const float* b1b    = (const float*)d_in[8];
    const float* g1     = (const float*)d_in[9];
    const float* be1    = (const float*)d_in[10];
    const float* eps2   = (const float*)d_in[11];
    const float* W2a    = (const float*)d_in[12];
    const float* b2a    = (const float*)d_in[13];
    const float* W2b    = (const float*)d_in[14];
    const float* b2b    = (const float*)d_in[15];
    const float* g2     = (const float*)d_in[16];
    const float* be2    = (const float*)d_in[17];
    const float* Wlin1  = (const float*)d_in[18];
    const float* blin1  = (const float*)d_in[19];
    const float* Wlin2  = (const float*)d_in[20];
    const float* blin2  = (const float*)d_in[21];
    const float* Wlin4  = (const float*)d_in[22];
    const float* blin4  = (const float*)d_in[23];
    const float* Wloss  = (const float*)d_in[24];
    const float* bloss  = (const float*)d_in[25];

    const int N  = in_sizes[0] / HF;
    const int E  = in_sizes[1] / 2;
    const int C_ = in_sizes[21];
    const int D_ = in_sizes[23];
    const int Gn = (out_size - 1) / (C_ + D_);
    const int NB = (N + BSZ - 1) >> BSH;

    const int* src = ei;
    const int* dst = ei + E;

    size_t NH = (size_t)N * HF;
    char* p = (char*)d_ws;
    unsigned short* xb  = (unsigned short*)p; p += NH * 2;
    unsigned short* U   = (unsigned short*)p; p += NH * 2;
    unsigned short* Hp1 = (unsigned short*)p; p += NH * 2;
    unsigned short* Hp2 = (unsigned short*)p; p += NH * 2;
    unsigned short* WtAll = (unsigned short*)p; p += 4 * 16384 * 2;
    float* S1a  = (float*)p; p += HF * 4;     // [S1a S2a S1b S2b] contiguous
    float* S2a  = (float*)p; p += HF * 4;
    float* S1b  = (float*)p; p += HF * 4;
    float* S2b  = (float*)p; p += HF * 4;
    int* gstart = (int*)p; p += (Gn + 1) * 4;
    int* boff   = (int*)p; p += (NBMAX + 1) * 4;
    int* bcur   = (int*)p; p += NBMAX * 4;
    int* bpart  = (int*)p; p += (size_t)NBMAX * HB * 4;
    int* off    = (int*)p; p += (N + 1) * 4;
    int* esrc   = (int*)p; p += E * 4;
    unsigned* ebuf = (unsigned*)p; p += E * 4;

    unsigned short* Wt1a = WtAll;
    unsigned short* Wt1b = WtAll + 16384;
    unsigned short* Wt2a = WtAll + 32768;
    unsigned short* Wt2b = WtAll + 49152;

    float* out1 = (float*)d_out;
    float* out3 = out1 + (size_t)Gn * C_;
    float* outm = out3 + (size_t)Gn * D_;

    int nchunks  = (int)(NH / 8);
    int castBlk  = (nchunks + 255) / 256;
    int nBlocks  = (N + 255) / 256;
    int gatherBlk = (N * 16 + 255) / 256;
    int gemmBlk  = (N + 63) / 64;
    int chunkH   = (E + HB - 1) / HB;
    float invN = 1.0f / (float)N;

    int initBlk = castBlk + 4 + HB + nBlocks + 1;

    // 1. mega-init: cast x, cast W, hist partials, graph bounds, zero stats+mse
    init_all<<<initBlk, 256, 0, stream>>>(x, xb, castBlk, nchunks,
                                          W1a, W1b, W2a, W2b, WtAll,
                                          dst, bpart, E, chunkH,
                                          batch, gstart, N, Gn, nBlocks,
                                          S1a, outm);
    // 2. bucket totals -> offsets + cursors
    scanp<<<1, 256, 0, stream>>>(bpart, boff, bcur, NB, E);
    // 3. bin edges (global chunk reservation, 512 blocks)
    bucket_bin<<<HB, 256, 0, stream>>>(src, dst, bcur, ebuf, E, NB, chunkH);
    // 4. per-bucket CSR fill
    bucket_fill<<<NB, 256, 0, stream>>>(ebuf, boff, off, esrc, N, NB, E);
    // 5-6. layer 1
    gather_u<false><<<gatherBlk, 256, 0, stream>>>(xb, off, esrc, eps1,
                                                   nullptr, nullptr, nullptr, nullptr, 0.f, U, N);
    gemm2L<<<gemmBlk, 256, 0, stream>>>(U, Wt1a, b1a, Wt1b, b1b, Hp1, S1a, S2a, N);
    // 7-8. layer 2 (BN1 finalize inline in gather)
    gather_u<true><<<gatherBlk, 256, 0, stream>>>(Hp1, off, esrc, eps2,
                                                  S1a, S2a, g1, be1, invN, U, N);
    gemm2L<<<gemmBlk, 256, 0, stream>>>(U, Wt2a, b2a, Wt2b, b2b, Hp2, S1b, S2b, N);
    // 9. tail: BN2 finalize inline + pool + lin1 + mse atomic + heads
    pool_tail<<<Gn, 512, 0, stream>>>(Hp2, S1b, S2b, g2, be2, invN, gstart,
                                      Wlin1, blin1, Wloss, bloss, degree,
                                      Wlin2, blin2, Wlin4, blin4,
                                      out1, out3, outm, C_, D_);
}

// Round 11
// 466.624 us; speedup vs baseline: 1.2468x; 1.0554x over previous
//
#include <hip/hip_runtime.h>
#include <hip/hip_bf16.h>

#define HF 128   // feature/hidden dim (F == H == 128)
#define BSH 8    // bucket shift: 256 nodes per bucket
#define BSZ 256
#define NBMAX 1024
#define FCAP 8192
#define AST 136  // padded LDS row stride (bf16 elems)
#define HB 512   // histogram/bin blocks

typedef __attribute__((ext_vector_type(8))) short bf16x8;
typedef __attribute__((ext_vector_type(4))) float f32x4;
typedef __attribute__((ext_vector_type(2))) float f32x2;

__device__ inline float bflo(unsigned u) { return __uint_as_float(u << 16); }
__device__ inline float bfhi(unsigned u) { return __uint_as_float(u & 0xffff0000u); }
__device__ inline unsigned short f2bf(float f) {
    unsigned u = __float_as_uint(f);
    unsigned r = (u + 0x7fffu + ((u >> 16) & 1u)) >> 16;
    return (unsigned short)r;
}
__device__ inline unsigned pack2(float a, float b) {
    return (unsigned)f2bf(a) | ((unsigned)f2bf(b) << 16);
}
// pack 8 floats -> 8 fp8 e4m3 (uint2)
__device__ inline uint2 pk8_fp8(const float* v) {
    int a = __builtin_amdgcn_cvt_pk_fp8_f32(v[0], v[1], 0, 0);
    a = __builtin_amdgcn_cvt_pk_fp8_f32(v[2], v[3], a, 1);
    int b = __builtin_amdgcn_cvt_pk_fp8_f32(v[4], v[5], 0, 0);
    b = __builtin_amdgcn_cvt_pk_fp8_f32(v[6], v[7], b, 1);
    uint2 r; r.x = (unsigned)a; r.y = (unsigned)b;
    return r;
}

// ============ mega-init: cast_x(bf16+fp8) | cast_wt | hist | bounds | zero ===
__global__ __launch_bounds__(256) void init_all(
    const float* __restrict__ x, unsigned short* __restrict__ xb,
    unsigned char* __restrict__ x8, int castBlk, int nchunks,
    const float* __restrict__ w0, const float* __restrict__ w1,
    const float* __restrict__ w2, const float* __restrict__ w3,
    unsigned short* __restrict__ WtAll,
    const int* __restrict__ dst, int* __restrict__ bpart, int E, int chunkH,
    const int* __restrict__ batch, int* __restrict__ gstart, int N, int Gn, int nBlocks,
    float* __restrict__ Szero, float* __restrict__ outm)
{
    __shared__ int lh[NBMAX];
    int b = blockIdx.x;
    int t = threadIdx.x;
    if (b < castBlk) {                       // ---- cast x -> bf16 + fp8
        int i = b * 256 + t;
        if (i < nchunks) {
            float4 a = ((const float4*)x)[2 * i];
            float4 c = ((const float4*)x)[2 * i + 1];
            uint4 o;
            o.x = pack2(a.x, a.y); o.y = pack2(a.z, a.w);
            o.z = pack2(c.x, c.y); o.w = pack2(c.z, c.w);
            ((uint4*)xb)[i] = o;
            float v[8] = {a.x, a.y, a.z, a.w, c.x, c.y, c.z, c.w};
            ((uint2*)x8)[i] = pk8_fp8(v);
        }
        return;
    }
    b -= castBlk;
    if (b < 4) {                             // ---- transpose-cast weights
        const float* W = (b == 0) ? w0 : (b == 1) ? w1 : (b == 2) ? w2 : w3;
        unsigned short* O = WtAll + b * 16384;
        for (int idx = t; idx < 16384; idx += 256) {
            int n = idx >> 7, k = idx & 127;
            O[idx] = f2bf(W[k * 128 + n]);
        }
        return;
    }
    b -= 4;
    if (b < HB) {                            // ---- histogram partials (transposed write)
        int NBl = (N + BSZ - 1) >> BSH;
        for (int i = t; i < NBl; i += 256) lh[i] = 0;
        __syncthreads();
        int beg = b * chunkH;
        int end = min(E, beg + chunkH);
        for (int e = beg + t; e < end; e += 256)
            atomicAdd(&lh[dst[e] >> BSH], 1);
        __syncthreads();
        for (int i = t; i < NBl; i += 256) bpart[i * HB + b] = lh[i];
        return;
    }
    b -= HB;
    if (b < nBlocks) {                       // ---- graph bounds
        int i = b * 256 + t;
        if (i >= N) return;
        int bi = batch[i];
        int bp = (i == 0) ? -1 : batch[i - 1];
        for (int g = bp + 1; g <= bi; g++) gstart[g] = i;
        if (i == N - 1)
            for (int g = bi + 1; g <= Gn; g++) gstart[g] = N;
        return;
    }
    if (t < 2 * HF) { Szero[t] = 0.f; Szero[t + 2 * HF] = 0.f; }
    if (t == 0) outm[0] = 0.f;
}

// ============ scan: bucket totals + boff/bcur ================================
__global__ void scanp(const int* __restrict__ bpart, int* __restrict__ boff,
                      int* __restrict__ bcur, int NB, int E)
{
    __shared__ int tot[NBMAX];
    __shared__ int part[256];
    int t = threadIdx.x;
    for (int i = t; i < NB; i += 256) {
        const int4* pp = (const int4*)(bpart + (size_t)i * HB);
        int run = 0;
#pragma unroll 4
        for (int b = 0; b < HB / 4; b++) {
            int4 v = pp[b];
            run += v.x + v.y + v.z + v.w;
        }
        tot[i] = run;
    }
    __syncthreads();
    int v[4];
    int s = 0;
#pragma unroll
    for (int i = 0; i < 4; i++) {
        int idx = t * 4 + i;
        v[i] = (idx < NB) ? tot[idx] : 0;
        s += v[i];
    }
    part[t] = s;
    __syncthreads();
    for (int o = 1; o < 256; o <<= 1) {
        int y = (t >= o) ? part[t - o] : 0;
        __syncthreads();
        part[t] += y;
        __syncthreads();
    }
    int base = part[t] - s;
#pragma unroll
    for (int i = 0; i < 4; i++) {
        int idx = t * 4 + i;
        if (idx < NB) { boff[idx] = base; bcur[idx] = base; base += v[i]; }
    }
    if (t == 0) boff[NB] = E;
}

// ============ bin edges =====================================================
__global__ __launch_bounds__(256) void bucket_bin(
    const int* __restrict__ src, const int* __restrict__ dst,
    int* __restrict__ bcur, unsigned* __restrict__ ebuf, int E, int NB, int chunkH)
{
    __shared__ int lh[NBMAX];
    int t = threadIdx.x;
    for (int i = t; i < NB; i += 256) lh[i] = 0;
    __syncthreads();
    int beg = blockIdx.x * chunkH;
    int end = min(E, beg + chunkH);
    for (int e = beg + t; e < end; e += 256)
        atomicAdd(&lh[dst[e] >> BSH], 1);
    __syncthreads();
    for (int i = t; i < NB; i += 256) {
        int c = lh[i];
        lh[i] = c ? atomicAdd(&bcur[i], c) : 0;
    }
    __syncthreads();
    for (int e = beg + t; e < end; e += 256) {
        int d = dst[e];
        int b = d >> BSH;
        int pos = atomicAdd(&lh[b], 1);
        ebuf[pos] = ((unsigned)src[e] << BSH) | (unsigned)(d & (BSZ - 1));
    }
}

// ============ per-bucket fill ================================================
__global__ __launch_bounds__(256) void bucket_fill(
    const unsigned* __restrict__ ebuf, const int* __restrict__ boff,
    int* __restrict__ off, int* __restrict__ esrc, int N, int NB, int E)
{
    __shared__ int deg[BSZ];
    __shared__ int pref[BSZ];
    __shared__ int lcur[BSZ];
    __shared__ int lsr[FCAP];
    int b = blockIdx.x;
    int t = threadIdx.x;
    int segBeg = boff[b], segEnd = boff[b + 1];
    int segLen = segEnd - segBeg;
    int node0 = b << BSH;
    deg[t] = 0;
    __syncthreads();
    for (int i = segBeg + t; i < segEnd; i += 256)
        atomicAdd(&deg[ebuf[i] & (BSZ - 1)], 1);
    __syncthreads();
    int dv = deg[t];
    pref[t] = dv;
    __syncthreads();
    for (int o = 1; o < 256; o <<= 1) {
        int y = (t >= o) ? pref[t - o] : 0;
        __syncthreads();
        pref[t] += y;
        __syncthreads();
    }
    int excl = pref[t] - dv;
    int node = node0 + t;
    if (node < N) off[node] = segBeg + excl;
    lcur[t] = excl;
    if (b == NB - 1 && t == 0) off[N] = E;
    __syncthreads();
    if (segLen <= FCAP) {
        for (int i = segBeg + t; i < segEnd; i += 256) {
            unsigned v = ebuf[i];
            int slot = atomicAdd(&lcur[v & (BSZ - 1)], 1);
            lsr[slot] = (int)(v >> BSH);
        }
        __syncthreads();
        for (int i = t; i < segLen; i += 256) esrc[segBeg + i] = lsr[i];
    } else {
        for (int i = segBeg + t; i < segEnd; i += 256) {
            unsigned v = ebuf[i];
            int slot = atomicAdd(&lcur[v & (BSZ - 1)], 1);
            esrc[segBeg + slot] = (int)(v >> BSH);
        }
    }
}

// ============ gather: neighbors from fp8 table, self from bf16 ==============
template <bool FOLD>
__global__ __launch_bounds__(256) void gather_u(
    const unsigned short* __restrict__ xb, const unsigned char* __restrict__ x8,
    const int* __restrict__ off, const int* __restrict__ esrc,
    const float* __restrict__ epsp,
    const float* __restrict__ S1, const float* __restrict__ S2,
    const float* __restrict__ gamma, const float* __restrict__ beta, float invN,
    unsigned short* __restrict__ Uo, int N)
{
    __shared__ float lsc[HF], lsh[HF];
    int tid = threadIdx.x;
    if (FOLD) {
        if (tid < HF) {
            float mu = S1[tid] * invN;
            float var = S2[tid] * invN - mu * mu;
            float rs = rsqrtf(var + 1e-5f);
            float sc = gamma[tid] * rs;
            lsc[tid] = sc;
            lsh[tid] = beta[tid] - mu * sc;
        }
        __syncthreads();
    }
    int lane16 = tid & 15;
    int node = (blockIdx.x * 256 + tid) >> 4;
    if (node >= N) return;
    int beg = off[node], end = off[node + 1];
    float acc[8] = {0.f, 0.f, 0.f, 0.f, 0.f, 0.f, 0.f, 0.f};
    for (int j0 = beg; j0 < end; j0 += 16) {
        int myidx = (j0 + lane16 < end) ? esrc[j0 + lane16] : 0;
        int cnt = min(16, end - j0);
        for (int t = 0; t < cnt; t++) {
            int s = __shfl(myidx, t, 16);
            uint2 p = *(const uint2*)(x8 + (size_t)s * HF + lane16 * 8);
            f32x2 f0 = __builtin_amdgcn_cvt_pk_f32_fp8((int)p.x, 0);
            f32x2 f1 = __builtin_amdgcn_cvt_pk_f32_fp8((int)p.x, 1);
            f32x2 f2 = __builtin_amdgcn_cvt_pk_f32_fp8((int)p.y, 0);
            f32x2 f3 = __builtin_amdgcn_cvt_pk_f32_fp8((int)p.y, 1);
            acc[0] += f0.x; acc[1] += f0.y;
            acc[2] += f1.x; acc[3] += f1.y;
            acc[4] += f2.x; acc[5] += f2.y;
            acc[6] += f3.x; acc[7] += f3.y;
        }
    }
    float ep = 1.0f + epsp[0];
    uint4 xx = *(const uint4*)(xb + (size_t)node * HF + lane16 * 8);
    acc[0] += ep * bflo(xx.x); acc[1] += ep * bfhi(xx.x);
    acc[2] += ep * bflo(xx.y); acc[3] += ep * bfhi(xx.y);
    acc[4] += ep * bflo(xx.z); acc[5] += ep * bfhi(xx.z);
    acc[6] += ep * bflo(xx.w); acc[7] += ep * bfhi(xx.w);
    if (FOLD) {
        float cf = ep + (float)(end - beg);
        const float4 s0 = *(const float4*)(&lsc[lane16 * 8]);
        const float4 s1 = *(const float4*)(&lsc[lane16 * 8 + 4]);
        const float4 h0 = *(const float4*)(&lsh[lane16 * 8]);
        const float4 h1 = *(const float4*)(&lsh[lane16 * 8 + 4]);
        acc[0] = acc[0] * s0.x + h0.x * cf; acc[1] = acc[1] * s0.y + h0.y * cf;
        acc[2] = acc[2] * s0.z + h0.z * cf; acc[3] = acc[3] * s0.w + h0.w * cf;
        acc[4] = acc[4] * s1.x + h1.x * cf; acc[5] = acc[5] * s1.y + h1.y * cf;
        acc[6] = acc[6] * s1.z + h1.z * cf; acc[7] = acc[7] * s1.w + h1.w * cf;
    }
    uint4 o;
    o.x = pack2(acc[0], acc[1]); o.y = pack2(acc[2], acc[3]);
    o.z = pack2(acc[4], acc[5]); o.w = pack2(acc[6], acc[7]);
    *(uint4*)(Uo + (size_t)node * HF + lane16 * 8) = o;
}

// ====== double-GEMM, LDS-staged W, wave-private row tiles ======
// out8 (optional): fp8 shadow of the bf16 output, for the next layer's gather.
__global__ __launch_bounds__(256) void gemm2L(
    const unsigned short* __restrict__ U,
    const unsigned short* __restrict__ Wta, const float* __restrict__ ba,
    const unsigned short* __restrict__ Wtb, const float* __restrict__ bb,
    unsigned short* __restrict__ out, unsigned char* __restrict__ out8,
    float* __restrict__ S1, float* __restrict__ S2, int n)
{
    __shared__ unsigned short lW[128 * AST];
    __shared__ unsigned short lT[64 * AST];
    __shared__ float lS1[HF], lS2[HF];
    int tid = threadIdx.x;
    int w = tid >> 6, lane = tid & 63;
    int m = lane & 15, quad = lane >> 4;
    int row0 = blockIdx.x * 64;
    if (tid < HF) { lS1[tid] = 0.f; lS2[tid] = 0.f; }

    for (int c = tid; c < 2048; c += 256) {       // Wa -> lW
        int r = c >> 4, k16 = c & 15;
        *(uint4*)(&lW[r * AST + k16 * 8]) = *(const uint4*)(Wta + r * HF + k16 * 8);
    }
    __syncthreads();

    int arow = row0 + w * 16 + m;
    if (arow >= n) arow = n - 1;                  // clamp; guarded below
    bf16x8 aF[4];
#pragma unroll
    for (int kk = 0; kk < 4; kk++)
        aF[kk] = *(const bf16x8*)(U + (size_t)arow * HF + kk * 32 + quad * 8);

    f32x4 acc[8];
#pragma unroll
    for (int nt = 0; nt < 8; nt++) acc[nt] = (f32x4){0.f, 0.f, 0.f, 0.f};
#pragma unroll
    for (int nt = 0; nt < 8; nt++) {
#pragma unroll
        for (int kk = 0; kk < 4; kk++) {
            bf16x8 b = *(const bf16x8*)(&lW[(nt * 16 + m) * AST + kk * 32 + quad * 8]);
            acc[nt] = __builtin_amdgcn_mfma_f32_16x16x32_bf16(aF[kk], b, acc[nt], 0, 0, 0);
        }
    }
#pragma unroll
    for (int nt = 0; nt < 8; nt++) {
        float bav = ba[nt * 16 + m];
#pragma unroll
        for (int r = 0; r < 4; r++) {
            int lrow = w * 16 + quad * 4 + r;
            lT[lrow * AST + nt * 16 + m] = f2bf(fmaxf(acc[nt][r] + bav, 0.f));
        }
    }
    __syncthreads();                               // all waves done with lW (Wa)
    for (int c = tid; c < 2048; c += 256) {        // Wb -> lW
        int r = c >> 4, k16 = c & 15;
        *(uint4*)(&lW[r * AST + k16 * 8]) = *(const uint4*)(Wtb + r * HF + k16 * 8);
    }
    __syncthreads();

#pragma unroll
    for (int kk = 0; kk < 4; kk++)
        aF[kk] = *(const bf16x8*)(&lT[(w * 16 + m) * AST + kk * 32 + quad * 8]);
#pragma unroll
    for (int nt = 0; nt < 8; nt++) acc[nt] = (f32x4){0.f, 0.f, 0.f, 0.f};
#pragma unroll
    for (int nt = 0; nt < 8; nt++) {
#pragma unroll
        for (int kk = 0; kk < 4; kk++) {
            bf16x8 b = *(const bf16x8*)(&lW[(nt * 16 + m) * AST + kk * 32 + quad * 8]);
            acc[nt] = __builtin_amdgcn_mfma_f32_16x16x32_bf16(aF[kk], b, acc[nt], 0, 0, 0);
        }
    }
#pragma unroll
    for (int nt = 0; nt < 8; nt++) {
        int col = nt * 16 + m;
        float bbv = bb[col];
        float cs = 0.f, cq = 0.f;
#pragma unroll
        for (int r = 0; r < 4; r++) {
            int lrow = w * 16 + quad * 4 + r;
            int grow = row0 + lrow;
            float v = fmaxf(acc[nt][r] + bbv, 0.f);
            lT[lrow * AST + col] = f2bf(v);
            if (grow < n) { cs += v; cq += v * v; }
        }
        cs += __shfl_down(cs, 32); cs += __shfl_down(cs, 16);
        cq += __shfl_down(cq, 32); cq += __shfl_down(cq, 16);
        if (quad == 0) { atomicAdd(&lS1[col], cs); atomicAdd(&lS2[col], cq); }
    }
#pragma unroll
    for (int i = 0; i < 4; i++) {
        int idx = i * 64 + lane;
        int r = idx >> 4, k16 = idx & 15;
        int grow = row0 + w * 16 + r;
        if (grow < n) {
            uint4 v = *(const uint4*)(&lT[(w * 16 + r) * AST + k16 * 8]);
            *(uint4*)(out + (size_t)grow * HF + k16 * 8) = v;
            if (out8) {
                float f[8] = {bflo(v.x), bfhi(v.x), bflo(v.y), bfhi(v.y),
                              bflo(v.z), bfhi(v.z), bflo(v.w), bfhi(v.w)};
                *(uint2*)(out8 + (size_t)grow * HF + k16 * 8) = pk8_fp8(f);
            }
        }
    }
    __syncthreads();
    if (tid < HF) { atomicAdd(&S1[tid], lS1[tid]); atomicAdd(&S2[tid], lS2[tid]); }
}

// ---- pool (BN2 inline) + lin1 + mse (atomic) + heads, one kernel/graph ----
__global__ __launch_bounds__(512) void pool_tail(
    const unsigned short* __restrict__ h2raw,
    const float* __restrict__ S1, const float* __restrict__ S2,
    const float* __restrict__ gamma, const float* __restrict__ beta, float invN,
    const int* __restrict__ gstart, const float* __restrict__ W,
    const float* __restrict__ bias,
    const float* __restrict__ Wloss, const float* __restrict__ blossp,
    const float* __restrict__ degree,
    const float* __restrict__ W2, const float* __restrict__ b2,
    const float* __restrict__ W4, const float* __restrict__ b4,
    float* __restrict__ out1, float* __restrict__ out3,
    float* __restrict__ outm, int C_, int D_)
{
    __shared__ float lsc[HF], lsh[HF];
    __shared__ float red[8][HF];
    __shared__ float gv[HF];
    __shared__ float part[4][HF];
    __shared__ float wred[8];
    __shared__ float zz[HF];
    __shared__ float logits[16];
    __shared__ float lse_s;
    int gid = blockIdx.x;
    int t = threadIdx.x;
    if (t < HF) {
        float mu = S1[t] * invN;
        float var = S2[t] * invN - mu * mu;
        float rs = rsqrtf(var + 1e-5f);
        float sc = gamma[t] * rs;
        lsc[t] = sc;
        lsh[t] = beta[t] - mu * sc;
    }
    __syncthreads();
    int c2 = t & 63;
    int rg = t >> 6;
    int b = gstart[gid], e = gstart[gid + 1];
    float wla = lsc[2 * c2] * Wloss[2 * c2];
    float wlb = lsc[2 * c2 + 1] * Wloss[2 * c2 + 1];
    float c0l = lsh[2 * c2] * Wloss[2 * c2] + lsh[2 * c2 + 1] * Wloss[2 * c2 + 1];
    float bl = blossp[0];
    float s0 = 0.f, s1 = 0.f, macc = 0.f;
    for (int r = b + rg; r < e; r += 8) {
        unsigned u = *(const unsigned*)(h2raw + (size_t)r * HF + c2 * 2);
        float v0 = bflo(u), v1 = bfhi(u);
        s0 += v0; s1 += v1;
        float m = v0 * wla + v1 * wlb + c0l;
#pragma unroll
        for (int o = 32; o > 0; o >>= 1) m += __shfl_down(m, o);
        if (c2 == 0) {
            float d = m + bl - degree[r];
            macc += d * d;
        }
    }
    red[rg][c2 * 2] = s0;
    red[rg][c2 * 2 + 1] = s1;
    if (c2 == 0) wred[rg] = macc;
    __syncthreads();
    if (t < HF) {
        float s = red[0][t] + red[1][t] + red[2][t] + red[3][t]
                + red[4][t] + red[5][t] + red[6][t] + red[7][t];
        gv[t] = (e > b) ? lsc[t] * (s / (float)(e - b)) + lsh[t] : 0.f;
    }
    __syncthreads();
    int c = t & 127, kg = t >> 7;
    float a = 0.f;
#pragma unroll 8
    for (int k = kg * 32; k < kg * 32 + 32; k++) a += gv[k] * W[(size_t)k * HF + c];
    part[kg][c] = a;
    __syncthreads();
    if (t < HF) {
        float aa = part[0][t] + part[1][t] + part[2][t] + part[3][t] + bias[t];
        zz[t] = fmaxf(aa, 0.f);
    }
    if (t == 0) {
        float ps = wred[0] + wred[1] + wred[2] + wred[3]
                 + wred[4] + wred[5] + wred[6] + wred[7];
        atomicAdd(outm, ps * invN);
    }
    __syncthreads();
    if (t < C_) {
        float aa = b2[t];
        for (int k = 0; k < HF; k++) aa += zz[k] * W2[(size_t)k * C_ + t];
        logits[t] = aa;
    }
    __syncthreads();
    if (t == 0) {
        float mx = -1e30f;
        for (int i = 0; i < C_; i++) mx = fmaxf(mx, logits[i]);
        float s = 0.f;
        for (int i = 0; i < C_; i++) s += expf(logits[i] - mx);
        lse_s = mx + logf(s);
    }
    __syncthreads();
    if (t < C_) out1[(size_t)gid * C_ + t] = logits[t] - lse_s;
    if (t < D_) {
        float aa = b4[t];
        for (int k = 0; k < HF; k++) aa += zz[k] * W4[(size_t)k * D_ + t];
        out3[(size_t)gid * D_ + t] = aa;
    }
}

extern "C" void kernel_launch(void* const* d_in, const int* in_sizes, int n_in,
                              void* d_out, int out_size, void* d_ws, size_t ws_size,
                              hipStream_t stream)
{
    const float* x      = (const float*)d_in[0];
    const int*   ei     = (const int*)d_in[1];
    const int*   batch  = (const int*)d_in[2];
    const float* degree = (const float*)d_in[3];
    const float* eps1   = (const float*)d_in[4];
    const float* W1a    = (const float*)d_in[5];
    const float* b1a    = (const float*)d_in[6];
    const float* W1b    = (const float*)d_in[7];
    const float* b1b    = (const float*)d_in[8];
    const float* g1     = (const float*)d_in[9];
    const float* be1    = (const float*)d_in[10];
    const float* eps2   = (const float*)d_in[11];
    const float* W2a    = (const float*)d_in[12];
    const float* b2a    = (const float*)d_in[13];
    const float* W2b    = (const float*)d_in[14];
    const float* b2b    = (const float*)d_in[15];
    const float* g2     = (const float*)d_in[16];
    const float* be2    = (const float*)d_in[17];
    const float* Wlin1  = (const float*)d_in[18];
    const float* blin1  = (const float*)d_in[19];
    const float* Wlin2  = (const float*)d_in[20];
    const float* blin2  = (const float*)d_in[21];
    const float* Wlin4  = (const float*)d_in[22];
    const float* blin4  = (const float*)d_in[23];
    const float* Wloss  = (const float*)d_in[24];
    const float* bloss  = (const float*)d_in[25];

    const int N  = in_sizes[0] / HF;
    const int E  = in_sizes[1] / 2;
    const int C_ = in_sizes[21];
    const int D_ = in_sizes[23];
    const int Gn = (out_size - 1) / (C_ + D_);
    const int NB = (N + BSZ - 1) >> BSH;

    const int* src = ei;
    const int* dst = ei + E;

    size_t NH = (size_t)N * HF;
    char* p = (char*)d_ws;
    unsigned short* xb  = (unsigned short*)p; p += NH * 2;
    unsigned short* U   = (unsigned short*)p; p += NH * 2;
    unsigned short* Hp1 = (unsigned short*)p; p += NH * 2;
    unsigned short* Hp2 = (unsigned short*)p; p += NH * 2;
    unsigned char*  x8  = (unsigned char*)p; p += NH;      // fp8 shadow of x
    unsigned char*  h8  = (unsigned char*)p; p += NH;      // fp8 shadow of Hp1
    unsigned short* WtAll = (unsigned short*)p; p += 4 * 16384 * 2;
    float* S1a  = (float*)p; p += HF * 4;     // [S1a S2a S1b S2b] contiguous
    float* S2a  = (float*)p; p += HF * 4;
    float* S1b  = (float*)p; p += HF * 4;
    float* S2b  = (float*)p; p += HF * 4;
    int* gstart = (int*)p; p += (Gn + 1) * 4;
    int* boff   = (int*)p; p += (NBMAX + 1) * 4;
    int* bcur   = (int*)p; p += NBMAX * 4;
    int* bpart  = (int*)p; p += (size_t)NBMAX * HB * 4;
    int* off    = (int*)p; p += (N + 1) * 4;
    int* esrc   = (int*)p; p += E * 4;
    unsigned* ebuf = (unsigned*)p; p += E * 4;

    unsigned short* Wt1a = WtAll;
    unsigned short* Wt1b = WtAll + 16384;
    unsigned short* Wt2a = WtAll + 32768;
    unsigned short* Wt2b = WtAll + 49152;

    float* out1 = (float*)d_out;
    float* out3 = out1 + (size_t)Gn * C_;
    float* outm = out3 + (size_t)Gn * D_;

    int nchunks  = (int)(NH / 8);
    int castBlk  = (nchunks + 255) / 256;
    int nBlocks  = (N + 255) / 256;
    int gatherBlk = (N * 16 + 255) / 256;
    int gemmBlk  = (N + 63) / 64;
    int chunkH   = (E + HB - 1) / HB;
    float invN = 1.0f / (float)N;

    int initBlk = castBlk + 4 + HB + nBlocks + 1;

    // 1. mega-init
    init_all<<<initBlk, 256, 0, stream>>>(x, xb, x8, castBlk, nchunks,
                                          W1a, W1b, W2a, W2b, WtAll,
                                          dst, bpart, E, chunkH,
                                          batch, gstart, N, Gn, nBlocks,
                                          S1a, outm);
    // 2. bucket totals -> offsets + cursors
    scanp<<<1, 256, 0, stream>>>(bpart, boff, bcur, NB, E);
    // 3. bin edges
    bucket_bin<<<HB, 256, 0, stream>>>(src, dst, bcur, ebuf, E, NB, chunkH);
    // 4. per-bucket CSR fill
    bucket_fill<<<NB, 256, 0, stream>>>(ebuf, boff, off, esrc, N, NB, E);
    // 5-6. layer 1 (gather neighbors from fp8 x8; gemm emits bf16 Hp1 + fp8 h8)
    gather_u<false><<<gatherBlk, 256, 0, stream>>>(xb, x8, off, esrc, eps1,
                                                   nullptr, nullptr, nullptr, nullptr, 0.f, U, N);
    gemm2L<<<gemmBlk, 256, 0, stream>>>(U, Wt1a, b1a, Wt1b, b1b, Hp1, h8, S1a, S2a, N);
    // 7-8. layer 2 (gather neighbors from fp8 h8; BN1 finalize inline)
    gather_u<true><<<gatherBlk, 256, 0, stream>>>(Hp1, h8, off, esrc, eps2,
                                                  S1a, S2a, g1, be1, invN, U, N);
    gemm2L<<<gemmBlk, 256, 0, stream>>>(U, Wt2a, b2a, Wt2b, b2b, Hp2, nullptr, S1b, S2b, N);
    // 9. tail
    pool_tail<<<Gn, 512, 0, stream>>>(Hp2, S1b, S2b, g2, be2, invN, gstart,
                                      Wlin1, blin1, Wloss, bloss, degree,
                                      Wlin2, blin2, Wlin4, blin4,
                                      out1, out3, outm, C_, D_);
}